// Round 1
// baseline (1133.808 us; speedup 1.0000x reference)
//
#include <hip/hip_runtime.h>
#include <math.h>

// Problem constants (from reference setup_inputs)
constexpr int NV  = 16000;   // voxels
constexpr int P   = 32;      // points per voxel
constexpr int CIN = 10;      // input channels
constexpr int CV  = 64;      // voxel feature channels
constexpr int NB  = 16000;   // BEV cells
constexpr int BEV_H = 496, BEV_W = 432;
constexpr int HW = BEV_H * BEV_W;  // 214272
constexpr float EPS = 1e-5f;

__device__ __forceinline__ float mish(float x) {
  // mish(x) = x * tanh(softplus(x)) = x * ((1+e)^2-1)/((1+e)^2+1), e = exp(x)
  float e = __expf(fminf(x, 15.f));          // clamp: for x>15, ratio==1 to fp32
  float n = fmaf(e, e, 2.f * e);             // (1+e)^2 - 1
  return x * __fdividef(n, n + 2.f);
}

// ---------------------------------------------------------------------------
// Kernel 1: VFE — 4 FELayers + mask/residual + max over points.
// Row(point)-per-lane; weights wave-uniform (scalar loads); raw layer outputs
// round-trip through a padded per-thread LDS slab to allow rolled output loop.
// ---------------------------------------------------------------------------
__global__ __launch_bounds__(128) void vfe_kernel(
    const float* __restrict__ voxels, const float* __restrict__ vmask,
    const float* __restrict__ W1, const float* __restrict__ g1, const float* __restrict__ b1,
    const float* __restrict__ W2, const float* __restrict__ g2, const float* __restrict__ b2,
    const float* __restrict__ W3, const float* __restrict__ g3, const float* __restrict__ b3,
    const float* __restrict__ W4, const float* __restrict__ g4, const float* __restrict__ b4,
    float* __restrict__ voxelwise)
{
  __shared__ float slab[128 * 65];           // 33.3 KB, stride 65 => 2-way banks (free)
  const int tid = threadIdx.x;
  const int pt  = blockIdx.x * 128 + tid;    // global point id
  const int v   = pt >> 5;                   // voxel id
  float* my = &slab[tid * 65];

  float xin[CIN];
#pragma unroll
  for (int c = 0; c < CIN; ++c) xin[c] = voxels[pt * CIN + c];
  const float m = vmask[pt];

  float xa[CV];    // current activations
  float x2r[CV];   // residual copy (x2)

  // ---- layer 1 (10 -> 64) ----
  float s1 = 0.f, s2 = 0.f;
#pragma unroll 1
  for (int o = 0; o < CV; ++o) {
    const float* wr = &W1[o * CIN];
    float acc = 0.f;
#pragma unroll
    for (int c = 0; c < CIN; ++c) acc = fmaf(xin[c], wr[c], acc);
    my[o] = acc; s1 += acc; s2 = fmaf(acc, acc, s2);
  }
  {
    float mean = s1 * (1.f / 64.f);
    float var  = fmaf(-mean, mean, s2 * (1.f / 64.f));
    float r = rsqrtf(var + EPS);
#pragma unroll
    for (int o = 0; o < CV; ++o)
      xa[o] = mish(fmaf((my[o] - mean) * r, g1[o], b1[o]));
  }

  // ---- layer 2 (64 -> 64), * mask, keep residual ----
  s1 = 0.f; s2 = 0.f;
#pragma unroll 1
  for (int o = 0; o < CV; ++o) {
    const float* wr = &W2[o * CV];
    float acc = 0.f;
#pragma unroll
    for (int c = 0; c < CV; ++c) acc = fmaf(xa[c], wr[c], acc);
    my[o] = acc; s1 += acc; s2 = fmaf(acc, acc, s2);
  }
  {
    float mean = s1 * (1.f / 64.f);
    float var  = fmaf(-mean, mean, s2 * (1.f / 64.f));
    float r = rsqrtf(var + EPS);
#pragma unroll
    for (int o = 0; o < CV; ++o) {
      float t = mish(fmaf((my[o] - mean) * r, g2[o], b2[o])) * m;
      xa[o] = t; x2r[o] = t;
    }
  }

  // ---- layer 3 (64 -> 64) ----
  s1 = 0.f; s2 = 0.f;
#pragma unroll 1
  for (int o = 0; o < CV; ++o) {
    const float* wr = &W3[o * CV];
    float acc = 0.f;
#pragma unroll
    for (int c = 0; c < CV; ++c) acc = fmaf(xa[c], wr[c], acc);
    my[o] = acc; s1 += acc; s2 = fmaf(acc, acc, s2);
  }
  {
    float mean = s1 * (1.f / 64.f);
    float var  = fmaf(-mean, mean, s2 * (1.f / 64.f));
    float r = rsqrtf(var + EPS);
#pragma unroll
    for (int o = 0; o < CV; ++o)
      xa[o] = mish(fmaf((my[o] - mean) * r, g3[o], b3[o]));
  }

  // ---- layer 4 (64 -> 64), * mask + residual, then max over 32 points ----
  s1 = 0.f; s2 = 0.f;
#pragma unroll 1
  for (int o = 0; o < CV; ++o) {
    const float* wr = &W4[o * CV];
    float acc = 0.f;
#pragma unroll
    for (int c = 0; c < CV; ++c) acc = fmaf(xa[c], wr[c], acc);
    my[o] = acc; s1 += acc; s2 = fmaf(acc, acc, s2);
  }
  {
    float mean = s1 * (1.f / 64.f);
    float var  = fmaf(-mean, mean, s2 * (1.f / 64.f));
    float r = rsqrtf(var + EPS);
#pragma unroll
    for (int o = 0; o < CV; ++o) {
      float val = fmaf(mish(fmaf((my[o] - mean) * r, g4[o], b4[o])), m, x2r[o]);
      float red = val;
      red = fmaxf(red, __shfl_xor(red, 1));
      red = fmaxf(red, __shfl_xor(red, 2));
      red = fmaxf(red, __shfl_xor(red, 4));
      red = fmaxf(red, __shfl_xor(red, 8));
      red = fmaxf(red, __shfl_xor(red, 16));
      if ((tid & 31) == 0) voxelwise[v * CV + o] = red;
    }
  }
}

// ---------------------------------------------------------------------------
// Kernel 2: BFE stage 1+2 — gather 64 voxels/cell, bfe1 (per-group 64x64),
// bfe2a (64->8), concat over p via LDS, bfe2b (32->8). Writes x17 [NB,128].
// Block: 64 cells x 4 waves (p = wave). Grid: (NB/64, 16 groups).
// ---------------------------------------------------------------------------
__global__ __launch_bounds__(256) void bfe12_kernel(
    const float* __restrict__ voxelwise, const int* __restrict__ bevsidx,
    const float* __restrict__ bevmask,
    const float* __restrict__ W1, const float* __restrict__ g1, const float* __restrict__ b1,
    const float* __restrict__ W2a, const float* __restrict__ g2a, const float* __restrict__ b2a,
    const float* __restrict__ W2b, const float* __restrict__ g2b, const float* __restrict__ b2b,
    float* __restrict__ x17buf)
{
  extern __shared__ float smem[];
  float* slab = smem;                 // 256*65
  float* lds2 = smem + 256 * 65;      // 64*33

  const int tid  = threadIdx.x;
  const int lane = tid & 63;
  const int p    = tid >> 6;
  const int g    = blockIdx.y;
  const int cell = blockIdx.x * 64 + lane;
  const int ch   = 4 * g + p;
  float* my = &slab[tid * 65];

  // gather input row: x[c] = voxelwise[bevsidx[cell][c]][4g+p]
  float x[CV];
#pragma unroll
  for (int c = 0; c < CV; ++c) {
    int idx = bevsidx[cell * 64 + c];
    x[c] = voxelwise[idx * CV + ch];
  }
  const float bm = bevmask[cell];

  // bfe1: 64 outputs
  float s1 = 0.f, s2 = 0.f;
#pragma unroll 1
  for (int o = 0; o < CV; ++o) {
    const float* wr = &W1[(g * 64 + o) * 64];
    float acc = 0.f;
#pragma unroll
    for (int c = 0; c < CV; ++c) acc = fmaf(x[c], wr[c], acc);
    my[o] = acc; s1 += acc; s2 = fmaf(acc, acc, s2);
  }
  float h[CV];
  {
    float mean = s1 * (1.f / 64.f);
    float var  = fmaf(-mean, mean, s2 * (1.f / 64.f));
    float r = rsqrtf(var + EPS);
#pragma unroll
    for (int o = 0; o < CV; ++o)
      h[o] = mish(fmaf((my[o] - mean) * r, g1[g * 64 + o], b1[g * 64 + o])) * bm;
  }

  // bfe2a: 8 outputs, LN over 8
  float h2[8];
  {
    float acc8[8];
#pragma unroll
    for (int o = 0; o < 8; ++o) {
      const float* wr = &W2a[(g * 8 + o) * 64];
      float acc = 0.f;
#pragma unroll
      for (int c = 0; c < CV; ++c) acc = fmaf(h[c], wr[c], acc);
      acc8[o] = acc;
    }
    float sa = 0.f, sb = 0.f;
#pragma unroll
    for (int o = 0; o < 8; ++o) { sa += acc8[o]; sb = fmaf(acc8[o], acc8[o], sb); }
    float mean = sa * 0.125f;
    float var  = fmaf(-mean, mean, sb * 0.125f);
    float r = rsqrtf(var + EPS);
#pragma unroll
    for (int o = 0; o < 8; ++o)
      h2[o] = mish(fmaf((acc8[o] - mean) * r, g2a[g * 8 + o], b2a[g * 8 + o]));
  }

  // concat over p through LDS: lds2[cell][p*8+o], stride 33
#pragma unroll
  for (int o = 0; o < 8; ++o) lds2[lane * 33 + p * 8 + o] = h2[o];
  __syncthreads();

  // bfe2b on wave 0: 32 -> 8, LN over 8
  if (p == 0) {
    float hc[32];
#pragma unroll
    for (int c = 0; c < 32; ++c) hc[c] = lds2[lane * 33 + c];
    float acc8[8];
#pragma unroll
    for (int o = 0; o < 8; ++o) {
      const float* wr = &W2b[(g * 8 + o) * 32];
      float acc = 0.f;
#pragma unroll
      for (int c = 0; c < 32; ++c) acc = fmaf(hc[c], wr[c], acc);
      acc8[o] = acc;
    }
    float sa = 0.f, sb = 0.f;
#pragma unroll
    for (int o = 0; o < 8; ++o) { sa += acc8[o]; sb = fmaf(acc8[o], acc8[o], sb); }
    float mean = sa * 0.125f;
    float var  = fmaf(-mean, mean, sb * 0.125f);
    float r = rsqrtf(var + EPS);
#pragma unroll
    for (int o = 0; o < 8; ++o)
      x17buf[cell * 128 + g * 8 + o] =
          mish(fmaf((acc8[o] - mean) * r, g2b[g * 8 + o], b2b[g * 8 + o]));
  }
}

// ---------------------------------------------------------------------------
// Kernel 3: bfe3 applied twice (shared weights) + residual + scatter.
// Block: 64 cells, 4 waves; wave w computes outputs o in [32w, 32w+32).
// LN over all 128 outputs via LDS partial sums.
// ---------------------------------------------------------------------------
__global__ __launch_bounds__(256) void bfe3_kernel(
    const float* __restrict__ x17buf, const int* __restrict__ bevcoors,
    const float* __restrict__ W3, const float* __restrict__ g3, const float* __restrict__ b3,
    float* __restrict__ out)
{
  extern __shared__ float smem[];
  float* ylds   = smem;                    // 64*129
  float* x18lds = smem + 64 * 129;         // 64*129
  float* ps1    = smem + 2 * 64 * 129;     // 4*64
  float* ps2    = ps1 + 4 * 64;            // 4*64

  const int tid  = threadIdx.x;
  const int lane = tid & 63;
  const int w    = tid >> 6;
  const int cell = blockIdx.x * 64 + lane;

  float xv[128];
#pragma unroll
  for (int c = 0; c < 128; ++c) xv[c] = x17buf[cell * 128 + c];

  // ---- layer A: x18_raw ----
  float s1 = 0.f, s2 = 0.f;
#pragma unroll 1
  for (int i = 0; i < 32; ++i) {
    const int o = 32 * w + i;
    const float* wr = &W3[o * 128];
    float acc = 0.f;
#pragma unroll
    for (int c = 0; c < 128; ++c) acc = fmaf(xv[c], wr[c], acc);
    ylds[lane * 129 + o] = acc; s1 += acc; s2 = fmaf(acc, acc, s2);
  }
  ps1[w * 64 + lane] = s1; ps2[w * 64 + lane] = s2;
  __syncthreads();
  {
    float S1 = ps1[lane] + ps1[64 + lane] + ps1[128 + lane] + ps1[192 + lane];
    float S2 = ps2[lane] + ps2[64 + lane] + ps2[128 + lane] + ps2[192 + lane];
    float mean = S1 * (1.f / 128.f);
    float var  = fmaf(-mean, mean, S2 * (1.f / 128.f));
    float r = rsqrtf(var + EPS);
#pragma unroll 1
    for (int i = 0; i < 32; ++i) {
      const int o = 32 * w + i;
      x18lds[lane * 129 + o] =
          mish(fmaf((ylds[lane * 129 + o] - mean) * r, g3[o], b3[o]));
    }
  }
  __syncthreads();

#pragma unroll
  for (int c = 0; c < 128; ++c) xv[c] = x18lds[lane * 129 + c];

  // ---- layer B: x19_raw ----
  s1 = 0.f; s2 = 0.f;
#pragma unroll 1
  for (int i = 0; i < 32; ++i) {
    const int o = 32 * w + i;
    const float* wr = &W3[o * 128];
    float acc = 0.f;
#pragma unroll
    for (int c = 0; c < 128; ++c) acc = fmaf(xv[c], wr[c], acc);
    ylds[lane * 129 + o] = acc; s1 += acc; s2 = fmaf(acc, acc, s2);
  }
  ps1[w * 64 + lane] = s1; ps2[w * 64 + lane] = s2;
  __syncthreads();
  {
    float S1 = ps1[lane] + ps1[64 + lane] + ps1[128 + lane] + ps1[192 + lane];
    float S2 = ps2[lane] + ps2[64 + lane] + ps2[128 + lane] + ps2[192 + lane];
    float mean = S1 * (1.f / 128.f);
    float var  = fmaf(-mean, mean, S2 * (1.f / 128.f));
    float r = rsqrtf(var + EPS);
    const int hq = bevcoors[cell * 2 + 0];
    const int wq = bevcoors[cell * 2 + 1];
#pragma unroll 1
    for (int i = 0; i < 32; ++i) {
      const int o = 32 * w + i;
      float val = mish(fmaf((ylds[lane * 129 + o] - mean) * r, g3[o], b3[o]))
                  + x17buf[cell * 128 + o];
      out[o * HW + wq * BEV_H + hq] = val;
    }
  }
}

// ---------------------------------------------------------------------------
extern "C" void kernel_launch(void* const* d_in, const int* in_sizes, int n_in,
                              void* d_out, int out_size, void* d_ws, size_t ws_size,
                              hipStream_t stream) {
  const float* voxels   = (const float*)d_in[0];
  const float* vmask    = (const float*)d_in[1];
  const int*   bevsidx  = (const int*)d_in[2];
  const int*   bevcoors = (const int*)d_in[3];
  const float* bevmask  = (const float*)d_in[4];
  const float* vfe1_W = (const float*)d_in[5];
  const float* vfe1_g = (const float*)d_in[6];
  const float* vfe1_b = (const float*)d_in[7];
  const float* vfe2_W = (const float*)d_in[8];
  const float* vfe2_g = (const float*)d_in[9];
  const float* vfe2_b = (const float*)d_in[10];
  const float* vfe3_W = (const float*)d_in[11];
  const float* vfe3_g = (const float*)d_in[12];
  const float* vfe3_b = (const float*)d_in[13];
  const float* vfe4_W = (const float*)d_in[14];
  const float* vfe4_g = (const float*)d_in[15];
  const float* vfe4_b = (const float*)d_in[16];
  const float* bfe1_W  = (const float*)d_in[17];
  const float* bfe1_g  = (const float*)d_in[18];
  const float* bfe1_b  = (const float*)d_in[19];
  const float* bfe2a_W = (const float*)d_in[20];
  const float* bfe2a_g = (const float*)d_in[21];
  const float* bfe2a_b = (const float*)d_in[22];
  const float* bfe2b_W = (const float*)d_in[23];
  const float* bfe2b_g = (const float*)d_in[24];
  const float* bfe2b_b = (const float*)d_in[25];
  const float* bfe3_W  = (const float*)d_in[26];
  const float* bfe3_g  = (const float*)d_in[27];
  const float* bfe3_b  = (const float*)d_in[28];

  float* voxelwise = (float*)d_ws;                    // NV*CV floats
  float* x17buf    = voxelwise + NV * CV;             // NB*128 floats
  float* out       = (float*)d_out;

  // zero the (mostly empty) BEV map
  hipMemsetAsync(d_out, 0, (size_t)out_size * sizeof(float), stream);

  vfe_kernel<<<NV * P / 128, 128, 0, stream>>>(
      voxels, vmask,
      vfe1_W, vfe1_g, vfe1_b, vfe2_W, vfe2_g, vfe2_b,
      vfe3_W, vfe3_g, vfe3_b, vfe4_W, vfe4_g, vfe4_b,
      voxelwise);

  size_t shB = (256 * 65 + 64 * 33) * sizeof(float);
  bfe12_kernel<<<dim3(NB / 64, 16), 256, shB, stream>>>(
      voxelwise, bevsidx, bevmask,
      bfe1_W, bfe1_g, bfe1_b, bfe2a_W, bfe2a_g, bfe2a_b,
      bfe2b_W, bfe2b_g, bfe2b_b, x17buf);

  size_t shC = (2 * 64 * 129 + 8 * 64) * sizeof(float);
  bfe3_kernel<<<NB / 64, 256, shC, stream>>>(
      x17buf, bevcoors, bfe3_W, bfe3_g, bfe3_b, out);
}

// Round 2
// 935.097 us; speedup vs baseline: 1.2125x; 1.2125x over previous
//
#include <hip/hip_runtime.h>
#include <math.h>

// Problem constants (from reference setup_inputs)
constexpr int NV  = 16000;   // voxels
constexpr int P   = 32;      // points per voxel
constexpr int CIN = 10;      // input channels
constexpr int CV  = 64;      // voxel feature channels
constexpr int NB  = 16000;   // BEV cells
constexpr int BEV_H = 496, BEV_W = 432;
constexpr int HW = BEV_H * BEV_W;  // 214272
constexpr float EPS = 1e-5f;

typedef __attribute__((ext_vector_type(8))) short short8_t;  // 8 bf16 (4 VGPR)
typedef __attribute__((ext_vector_type(4))) short short4_t;  // 4 bf16
typedef __attribute__((ext_vector_type(4))) float fx4;       // MFMA C/D frag

__device__ __forceinline__ float mish(float x) {
  // mish(x) = x * tanh(softplus(x)) = x * ((1+e)^2-1)/((1+e)^2+1), e = exp(x)
  float e = __expf(fminf(x, 15.f));
  float n = fmaf(e, e, 2.f * e);
  return x * __fdividef(n, n + 2.f);
}

__device__ __forceinline__ short f2bf(float f) {
  // round-to-nearest-even f32 -> bf16 bits (finite inputs)
  unsigned u = __builtin_bit_cast(unsigned, f);
  u += 0x7FFF + ((u >> 16) & 1);
  return (short)(u >> 16);
}

__device__ __forceinline__ short8_t pack8(const float* t) {
  short8_t s;
#pragma unroll
  for (int j = 0; j < 8; ++j) s[j] = f2bf(t[j]);
  return s;
}

// ---------------------------------------------------------------------------
// VFE via bf16 MFMA.  D = W·X^T per 16-point tile:
//   A-frag  = W[o=lane&15 + 16f][c=8q+j+32ch]   (weights resident in VGPRs)
//   B-frag  = X[p=lane&15][c=8q+j+32ch]         (from wave-private LDS, bf16)
//   D-frag  : lane holds channels {4q+r+16f} of point p=lane&15 (fp32)
// LN per point = in-lane sum of 16 + shfl_xor(16,32).  LN/mish/mask/residual
// in fp32.  Inter-layer C->B transform through wave-private LDS (same-wave
// in-order DS, no barriers).  Max over 32 points via fp32 LDS scratch, final
// store one coalesced dword per lane (lane = channel).
// Grid: 500 blocks x 4 waves = 2000 waves, 8 voxels each (exactly NV).
// ---------------------------------------------------------------------------
__global__ __launch_bounds__(256, 2) void vfe_mfma_kernel(
    const float* __restrict__ voxels, const float* __restrict__ vmask,
    const float* __restrict__ W1, const float* __restrict__ g1, const float* __restrict__ b1,
    const float* __restrict__ W2, const float* __restrict__ g2, const float* __restrict__ b2,
    const float* __restrict__ W3, const float* __restrict__ g3, const float* __restrict__ b3,
    const float* __restrict__ W4, const float* __restrict__ g4, const float* __restrict__ b4,
    float* __restrict__ voxelwise)
{
  __shared__ short act_buf[4][16 * 72];   // bf16 activations, stride 72 (b128-aligned, balanced banks)
  __shared__ float max_buf[4][16 * 68];   // fp32 x4 scratch for point-max, stride 68

  const int tid  = threadIdx.x;
  const int lane = tid & 63;
  const int w    = tid >> 6;            // wave in block
  const int p    = lane & 15;           // point-in-tile / D col
  const int q    = lane >> 4;           // quad
  const int gw   = blockIdx.x * 4 + w;  // global wave id (0..1999)

  short* mybuf = &act_buf[w][0];
  float* mymax = &max_buf[w][0];

  // ---- preload weight A-frags into VGPRs (112 VGPR) ----
  short8_t w1f[4];
#pragma unroll
  for (int f = 0; f < 4; ++f) {
    float t[8];
#pragma unroll
    for (int j = 0; j < 8; ++j) {
      int c = 8 * q + j;
      t[j] = (c < CIN) ? W1[(p + 16 * f) * CIN + c] : 0.f;
    }
    w1f[f] = pack8(t);
  }
  short8_t wf[3][4][2];
  const float* Ws[3] = {W2, W3, W4};
#pragma unroll
  for (int l = 0; l < 3; ++l)
#pragma unroll
    for (int f = 0; f < 4; ++f)
#pragma unroll
      for (int ch = 0; ch < 2; ++ch) {
        const float* src = Ws[l] + (p + 16 * f) * CV + 32 * ch + 8 * q;
        float t[8];
#pragma unroll
        for (int j = 0; j < 8; ++j) t[j] = src[j];
        wf[l][f][ch] = pack8(t);
      }

  const fx4 zacc = {0.f, 0.f, 0.f, 0.f};

  for (int i = 0; i < 8; ++i) {
    const int v = gw * 8 + i;
    float chmax0 = 0.f;   // channel max of half 0 (set in h==0)
    float vmaxv  = 0.f;

    for (int h = 0; h < 2; ++h) {
      const int ptbase = v * 32 + h * 16;
      const float m = vmask[ptbase + p];   // my point's mask
      float x2r[16];                       // residual (fp32)

      // ---- layer 1: B-frag from global (K=10 padded to 32) ----
      {
        const float* xrow = voxels + (size_t)(ptbase + p) * CIN;
        float t[8];
#pragma unroll
        for (int j = 0; j < 8; ++j) {
          int c = 8 * q + j;
          t[j] = (c < CIN) ? xrow[c] : 0.f;
        }
        short8_t bfrag = pack8(t);
        fx4 acc[4];
#pragma unroll
        for (int f = 0; f < 4; ++f)
          acc[f] = __builtin_amdgcn_mfma_f32_16x16x32_bf16(w1f[f], bfrag, zacc, 0, 0, 0);

        float s1 = 0.f, s2 = 0.f;
#pragma unroll
        for (int f = 0; f < 4; ++f)
#pragma unroll
          for (int r = 0; r < 4; ++r) { float x = acc[f][r]; s1 += x; s2 = fmaf(x, x, s2); }
        s1 += __shfl_xor(s1, 16); s1 += __shfl_xor(s1, 32);
        s2 += __shfl_xor(s2, 16); s2 += __shfl_xor(s2, 32);
        float mean = s1 * (1.f / 64.f);
        float rstd = rsqrtf(fmaf(-mean, mean, s2 * (1.f / 64.f)) + EPS);
#pragma unroll
        for (int f = 0; f < 4; ++f) {
          float4 gv = *(const float4*)(g1 + 4 * q + 16 * f);
          float4 bv = *(const float4*)(b1 + 4 * q + 16 * f);
          float go[4] = {gv.x, gv.y, gv.z, gv.w};
          float bo[4] = {bv.x, bv.y, bv.z, bv.w};
          short4_t s4;
#pragma unroll
          for (int r = 0; r < 4; ++r) {
            float t1 = fmaf((acc[f][r] - mean) * rstd, go[r], bo[r]);
            s4[r] = f2bf(mish(t1));
          }
          *(short4_t*)&mybuf[p * 72 + 4 * q + 16 * f] = s4;
        }
      }

      // ---- layers 2..4 ----
#pragma unroll 1
      for (int l = 0; l < 3; ++l) {
        short8_t bf0 = *(short8_t*)&mybuf[p * 72 + 8 * q];        // chunk 0
        short8_t bf1 = *(short8_t*)&mybuf[p * 72 + 8 * q + 32];   // chunk 1
        fx4 acc[4];
#pragma unroll
        for (int f = 0; f < 4; ++f) {
          acc[f] = __builtin_amdgcn_mfma_f32_16x16x32_bf16(wf[l][f][0], bf0, zacc, 0, 0, 0);
          acc[f] = __builtin_amdgcn_mfma_f32_16x16x32_bf16(wf[l][f][1], bf1, acc[f], 0, 0, 0);
        }
        float s1 = 0.f, s2 = 0.f;
#pragma unroll
        for (int f = 0; f < 4; ++f)
#pragma unroll
          for (int r = 0; r < 4; ++r) { float x = acc[f][r]; s1 += x; s2 = fmaf(x, x, s2); }
        s1 += __shfl_xor(s1, 16); s1 += __shfl_xor(s1, 32);
        s2 += __shfl_xor(s2, 16); s2 += __shfl_xor(s2, 32);
        float mean = s1 * (1.f / 64.f);
        float rstd = rsqrtf(fmaf(-mean, mean, s2 * (1.f / 64.f)) + EPS);

        const float* gp = (l == 0) ? g2 : (l == 1) ? g3 : g4;
        const float* bp = (l == 0) ? b2 : (l == 1) ? b3 : b4;
#pragma unroll
        for (int f = 0; f < 4; ++f) {
          float4 gv = *(const float4*)(gp + 4 * q + 16 * f);
          float4 bv = *(const float4*)(bp + 4 * q + 16 * f);
          float go[4] = {gv.x, gv.y, gv.z, gv.w};
          float bo[4] = {bv.x, bv.y, bv.z, bv.w};
          if (l == 0) {            // layer 2: *mask, keep residual
            short4_t s4;
#pragma unroll
            for (int r = 0; r < 4; ++r) {
              float t1 = fmaf((acc[f][r] - mean) * rstd, go[r], bo[r]);
              float a  = mish(t1) * m;
              x2r[f * 4 + r] = a;
              s4[r] = f2bf(a);
            }
            *(short4_t*)&mybuf[p * 72 + 4 * q + 16 * f] = s4;
          } else if (l == 1) {     // layer 3
            short4_t s4;
#pragma unroll
            for (int r = 0; r < 4; ++r) {
              float t1 = fmaf((acc[f][r] - mean) * rstd, go[r], bo[r]);
              s4[r] = f2bf(mish(t1));
            }
            *(short4_t*)&mybuf[p * 72 + 4 * q + 16 * f] = s4;
          } else {                 // layer 4: *mask + residual -> fp32 scratch
            fx4 xf;
#pragma unroll
            for (int r = 0; r < 4; ++r) {
              float t1 = fmaf((acc[f][r] - mean) * rstd, go[r], bo[r]);
              xf[r] = fmaf(mish(t1), m, x2r[f * 4 + r]);
            }
            *(fx4*)&mymax[p * 68 + 4 * q + 16 * f] = xf;
          }
        }
      }

      // ---- max over the 16 points of this half (lane = channel) ----
      float mx = -3.4e38f;
#pragma unroll
      for (int pp = 0; pp < 16; ++pp) mx = fmaxf(mx, mymax[pp * 68 + lane]);
      if (h == 0) chmax0 = mx; else vmaxv = fmaxf(chmax0, mx);
    }

    voxelwise[v * 64 + lane] = vmaxv;   // coalesced
  }
}

// ---------------------------------------------------------------------------
// Kernel 2: BFE stage 1+2 (unchanged fp32 this round)
// ---------------------------------------------------------------------------
__global__ __launch_bounds__(256) void bfe12_kernel(
    const float* __restrict__ voxelwise, const int* __restrict__ bevsidx,
    const float* __restrict__ bevmask,
    const float* __restrict__ W1, const float* __restrict__ g1, const float* __restrict__ b1,
    const float* __restrict__ W2a, const float* __restrict__ g2a, const float* __restrict__ b2a,
    const float* __restrict__ W2b, const float* __restrict__ g2b, const float* __restrict__ b2b,
    float* __restrict__ x17buf)
{
  extern __shared__ float smem[];
  float* slab = smem;                 // 256*65
  float* lds2 = smem + 256 * 65;      // 64*33

  const int tid  = threadIdx.x;
  const int lane = tid & 63;
  const int p    = tid >> 6;
  const int g    = blockIdx.y;
  const int cell = blockIdx.x * 64 + lane;
  const int ch   = 4 * g + p;
  float* my = &slab[tid * 65];

  float x[CV];
#pragma unroll
  for (int c = 0; c < CV; ++c) {
    int idx = bevsidx[cell * 64 + c];
    x[c] = voxelwise[idx * CV + ch];
  }
  const float bm = bevmask[cell];

  float s1 = 0.f, s2 = 0.f;
#pragma unroll 1
  for (int o = 0; o < CV; ++o) {
    const float* wr = &W1[(g * 64 + o) * 64];
    float acc = 0.f;
#pragma unroll
    for (int c = 0; c < CV; ++c) acc = fmaf(x[c], wr[c], acc);
    my[o] = acc; s1 += acc; s2 = fmaf(acc, acc, s2);
  }
  float h[CV];
  {
    float mean = s1 * (1.f / 64.f);
    float var  = fmaf(-mean, mean, s2 * (1.f / 64.f));
    float r = rsqrtf(var + EPS);
#pragma unroll
    for (int o = 0; o < CV; ++o)
      h[o] = mish(fmaf((my[o] - mean) * r, g1[g * 64 + o], b1[g * 64 + o])) * bm;
  }

  float h2[8];
  {
    float acc8[8];
#pragma unroll
    for (int o = 0; o < 8; ++o) {
      const float* wr = &W2a[(g * 8 + o) * 64];
      float acc = 0.f;
#pragma unroll
      for (int c = 0; c < CV; ++c) acc = fmaf(h[c], wr[c], acc);
      acc8[o] = acc;
    }
    float sa = 0.f, sb = 0.f;
#pragma unroll
    for (int o = 0; o < 8; ++o) { sa += acc8[o]; sb = fmaf(acc8[o], acc8[o], sb); }
    float mean = sa * 0.125f;
    float var  = fmaf(-mean, mean, sb * 0.125f);
    float r = rsqrtf(var + EPS);
#pragma unroll
    for (int o = 0; o < 8; ++o)
      h2[o] = mish(fmaf((acc8[o] - mean) * r, g2a[g * 8 + o], b2a[g * 8 + o]));
  }

#pragma unroll
  for (int o = 0; o < 8; ++o) lds2[lane * 33 + p * 8 + o] = h2[o];
  __syncthreads();

  if (p == 0) {
    float hc[32];
#pragma unroll
    for (int c = 0; c < 32; ++c) hc[c] = lds2[lane * 33 + c];
    float acc8[8];
#pragma unroll
    for (int o = 0; o < 8; ++o) {
      const float* wr = &W2b[(g * 8 + o) * 32];
      float acc = 0.f;
#pragma unroll
      for (int c = 0; c < 32; ++c) acc = fmaf(hc[c], wr[c], acc);
      acc8[o] = acc;
    }
    float sa = 0.f, sb = 0.f;
#pragma unroll
    for (int o = 0; o < 8; ++o) { sa += acc8[o]; sb = fmaf(acc8[o], acc8[o], sb); }
    float mean = sa * 0.125f;
    float var  = fmaf(-mean, mean, sb * 0.125f);
    float r = rsqrtf(var + EPS);
#pragma unroll
    for (int o = 0; o < 8; ++o)
      x17buf[cell * 128 + g * 8 + o] =
          mish(fmaf((acc8[o] - mean) * r, g2b[g * 8 + o], b2b[g * 8 + o]));
  }
}

// ---------------------------------------------------------------------------
// Kernel 3: bfe3 twice + residual + scatter (unchanged fp32 this round)
// ---------------------------------------------------------------------------
__global__ __launch_bounds__(256) void bfe3_kernel(
    const float* __restrict__ x17buf, const int* __restrict__ bevcoors,
    const float* __restrict__ W3, const float* __restrict__ g3, const float* __restrict__ b3,
    float* __restrict__ out)
{
  extern __shared__ float smem[];
  float* ylds   = smem;                    // 64*129
  float* x18lds = smem + 64 * 129;         // 64*129
  float* ps1    = smem + 2 * 64 * 129;     // 4*64
  float* ps2    = ps1 + 4 * 64;            // 4*64

  const int tid  = threadIdx.x;
  const int lane = tid & 63;
  const int w    = tid >> 6;
  const int cell = blockIdx.x * 64 + lane;

  float xv[128];
#pragma unroll
  for (int c = 0; c < 128; ++c) xv[c] = x17buf[cell * 128 + c];

  float s1 = 0.f, s2 = 0.f;
#pragma unroll 1
  for (int i = 0; i < 32; ++i) {
    const int o = 32 * w + i;
    const float* wr = &W3[o * 128];
    float acc = 0.f;
#pragma unroll
    for (int c = 0; c < 128; ++c) acc = fmaf(xv[c], wr[c], acc);
    ylds[lane * 129 + o] = acc; s1 += acc; s2 = fmaf(acc, acc, s2);
  }
  ps1[w * 64 + lane] = s1; ps2[w * 64 + lane] = s2;
  __syncthreads();
  {
    float S1 = ps1[lane] + ps1[64 + lane] + ps1[128 + lane] + ps1[192 + lane];
    float S2 = ps2[lane] + ps2[64 + lane] + ps2[128 + lane] + ps2[192 + lane];
    float mean = S1 * (1.f / 128.f);
    float var  = fmaf(-mean, mean, S2 * (1.f / 128.f));
    float r = rsqrtf(var + EPS);
#pragma unroll 1
    for (int i = 0; i < 32; ++i) {
      const int o = 32 * w + i;
      x18lds[lane * 129 + o] =
          mish(fmaf((ylds[lane * 129 + o] - mean) * r, g3[o], b3[o]));
    }
  }
  __syncthreads();

#pragma unroll
  for (int c = 0; c < 128; ++c) xv[c] = x18lds[lane * 129 + c];

  s1 = 0.f; s2 = 0.f;
#pragma unroll 1
  for (int i = 0; i < 32; ++i) {
    const int o = 32 * w + i;
    const float* wr = &W3[o * 128];
    float acc = 0.f;
#pragma unroll
    for (int c = 0; c < 128; ++c) acc = fmaf(xv[c], wr[c], acc);
    ylds[lane * 129 + o] = acc; s1 += acc; s2 = fmaf(acc, acc, s2);
  }
  ps1[w * 64 + lane] = s1; ps2[w * 64 + lane] = s2;
  __syncthreads();
  {
    float S1 = ps1[lane] + ps1[64 + lane] + ps1[128 + lane] + ps1[192 + lane];
    float S2 = ps2[lane] + ps2[64 + lane] + ps2[128 + lane] + ps2[192 + lane];
    float mean = S1 * (1.f / 128.f);
    float var  = fmaf(-mean, mean, S2 * (1.f / 128.f));
    float r = rsqrtf(var + EPS);
    const int hq = bevcoors[cell * 2 + 0];
    const int wq = bevcoors[cell * 2 + 1];
#pragma unroll 1
    for (int i = 0; i < 32; ++i) {
      const int o = 32 * w + i;
      float val = mish(fmaf((ylds[lane * 129 + o] - mean) * r, g3[o], b3[o]))
                  + x17buf[cell * 128 + o];
      out[o * HW + wq * BEV_H + hq] = val;
    }
  }
}

// ---------------------------------------------------------------------------
extern "C" void kernel_launch(void* const* d_in, const int* in_sizes, int n_in,
                              void* d_out, int out_size, void* d_ws, size_t ws_size,
                              hipStream_t stream) {
  const float* voxels   = (const float*)d_in[0];
  const float* vmask    = (const float*)d_in[1];
  const int*   bevsidx  = (const int*)d_in[2];
  const int*   bevcoors = (const int*)d_in[3];
  const float* bevmask  = (const float*)d_in[4];
  const float* vfe1_W = (const float*)d_in[5];
  const float* vfe1_g = (const float*)d_in[6];
  const float* vfe1_b = (const float*)d_in[7];
  const float* vfe2_W = (const float*)d_in[8];
  const float* vfe2_g = (const float*)d_in[9];
  const float* vfe2_b = (const float*)d_in[10];
  const float* vfe3_W = (const float*)d_in[11];
  const float* vfe3_g = (const float*)d_in[12];
  const float* vfe3_b = (const float*)d_in[13];
  const float* vfe4_W = (const float*)d_in[14];
  const float* vfe4_g = (const float*)d_in[15];
  const float* vfe4_b = (const float*)d_in[16];
  const float* bfe1_W  = (const float*)d_in[17];
  const float* bfe1_g  = (const float*)d_in[18];
  const float* bfe1_b  = (const float*)d_in[19];
  const float* bfe2a_W = (const float*)d_in[20];
  const float* bfe2a_g = (const float*)d_in[21];
  const float* bfe2a_b = (const float*)d_in[22];
  const float* bfe2b_W = (const float*)d_in[23];
  const float* bfe2b_g = (const float*)d_in[24];
  const float* bfe2b_b = (const float*)d_in[25];
  const float* bfe3_W  = (const float*)d_in[26];
  const float* bfe3_g  = (const float*)d_in[27];
  const float* bfe3_b  = (const float*)d_in[28];

  float* voxelwise = (float*)d_ws;                    // NV*CV floats
  float* x17buf    = voxelwise + NV * CV;             // NB*128 floats
  float* out       = (float*)d_out;

  hipMemsetAsync(d_out, 0, (size_t)out_size * sizeof(float), stream);

  vfe_mfma_kernel<<<500, 256, 0, stream>>>(
      voxels, vmask,
      vfe1_W, vfe1_g, vfe1_b, vfe2_W, vfe2_g, vfe2_b,
      vfe3_W, vfe3_g, vfe3_b, vfe4_W, vfe4_g, vfe4_b,
      voxelwise);

  size_t shB = (256 * 65 + 64 * 33) * sizeof(float);
  bfe12_kernel<<<dim3(NB / 64, 16), 256, shB, stream>>>(
      voxelwise, bevsidx, bevmask,
      bfe1_W, bfe1_g, bfe1_b, bfe2a_W, bfe2a_g, bfe2a_b,
      bfe2b_W, bfe2b_g, bfe2b_b, x17buf);

  size_t shC = (2 * 64 * 129 + 8 * 64) * sizeof(float);
  bfe3_kernel<<<NB / 64, 256, shC, stream>>>(
      x17buf, bevcoors, bfe3_W, bfe3_g, bfe3_b, out);
}

// Round 3
// 723.709 us; speedup vs baseline: 1.5667x; 1.2921x over previous
//
#include <hip/hip_runtime.h>
#include <math.h>

// Problem constants (from reference setup_inputs)
constexpr int NV  = 16000;   // voxels
constexpr int P   = 32;      // points per voxel
constexpr int CIN = 10;      // input channels
constexpr int CV  = 64;      // voxel feature channels
constexpr int NB  = 16000;   // BEV cells
constexpr int BEV_H = 496, BEV_W = 432;
constexpr int HW = BEV_H * BEV_W;  // 214272
constexpr float EPS = 1e-5f;

typedef __attribute__((ext_vector_type(8))) short short8_t;  // 8 bf16 (4 VGPR)
typedef __attribute__((ext_vector_type(4))) short short4_t;  // 4 bf16
typedef __attribute__((ext_vector_type(4))) float fx4;       // MFMA C/D frag

__device__ __forceinline__ float mish(float x) {
  float e = __expf(fminf(x, 15.f));
  float n = fmaf(e, e, 2.f * e);
  return x * __fdividef(n, n + 2.f);
}

__device__ __forceinline__ short f2bf(float f) {
  unsigned u = __builtin_bit_cast(unsigned, f);
  u += 0x7FFF + ((u >> 16) & 1);
  return (short)(u >> 16);
}
__device__ __forceinline__ float bf2f(short s) {
  unsigned u = ((unsigned)(unsigned short)s) << 16;
  return __builtin_bit_cast(float, u);
}
__device__ __forceinline__ short8_t pack8(const float* t) {
  short8_t s;
#pragma unroll
  for (int j = 0; j < 8; ++j) s[j] = f2bf(t[j]);
  return s;
}

// ---------------------------------------------------------------------------
// Prologue: split bfe weights into bf16 hi/lo, zero-padding o-dim to 16 for
// W2a/W2b. Layouts: W1[g][64][64], W2a_pad[g][16][64], W2b_pad[g][16][32].
// ---------------------------------------------------------------------------
__global__ __launch_bounds__(256) void pack_weights_kernel(
    const float* __restrict__ W1, const float* __restrict__ W2a,
    const float* __restrict__ W2b,
    short* __restrict__ w1h, short* __restrict__ w1l,
    short* __restrict__ w2ah, short* __restrict__ w2al,
    short* __restrict__ w2bh, short* __restrict__ w2bl)
{
  int i = blockIdx.x * 256 + threadIdx.x;
  if (i < 65536) {
    float v = W1[i];
    short h = f2bf(v);
    w1h[i] = h; w1l[i] = f2bf(v - bf2f(h));
  } else if (i < 81920) {
    int j = i - 65536;
    int g = j >> 10, o = (j >> 6) & 15, c = j & 63;
    float v = (o < 8) ? W2a[(g * 8 + o) * 64 + c] : 0.f;
    short h = f2bf(v);
    w2ah[j] = h; w2al[j] = f2bf(v - bf2f(h));
  } else if (i < 90112) {
    int k = i - 81920;
    int g = k >> 9, o = (k >> 5) & 15, c = k & 31;
    float v = (o < 8) ? W2b[(g * 8 + o) * 32 + c] : 0.f;
    short h = f2bf(v);
    w2bh[k] = h; w2bl[k] = f2bf(v - bf2f(h));
  }
}

// ---------------------------------------------------------------------------
// VFE via bf16 MFMA (unchanged from round 2 — passing at ~0.0625 absmax).
// ---------------------------------------------------------------------------
__global__ __launch_bounds__(256, 2) void vfe_mfma_kernel(
    const float* __restrict__ voxels, const float* __restrict__ vmask,
    const float* __restrict__ W1, const float* __restrict__ g1, const float* __restrict__ b1,
    const float* __restrict__ W2, const float* __restrict__ g2, const float* __restrict__ b2,
    const float* __restrict__ W3, const float* __restrict__ g3, const float* __restrict__ b3,
    const float* __restrict__ W4, const float* __restrict__ g4, const float* __restrict__ b4,
    float* __restrict__ voxelwise)
{
  __shared__ short act_buf[4][16 * 72];
  __shared__ float max_buf[4][16 * 68];

  const int tid  = threadIdx.x;
  const int lane = tid & 63;
  const int w    = tid >> 6;
  const int p    = lane & 15;
  const int q    = lane >> 4;
  const int gw   = blockIdx.x * 4 + w;

  short* mybuf = &act_buf[w][0];
  float* mymax = &max_buf[w][0];

  short8_t w1f[4];
#pragma unroll
  for (int f = 0; f < 4; ++f) {
    float t[8];
#pragma unroll
    for (int j = 0; j < 8; ++j) {
      int c = 8 * q + j;
      t[j] = (c < CIN) ? W1[(p + 16 * f) * CIN + c] : 0.f;
    }
    w1f[f] = pack8(t);
  }
  short8_t wf[3][4][2];
  const float* Ws[3] = {W2, W3, W4};
#pragma unroll
  for (int l = 0; l < 3; ++l)
#pragma unroll
    for (int f = 0; f < 4; ++f)
#pragma unroll
      for (int ch = 0; ch < 2; ++ch) {
        const float* src = Ws[l] + (p + 16 * f) * CV + 32 * ch + 8 * q;
        float t[8];
#pragma unroll
        for (int j = 0; j < 8; ++j) t[j] = src[j];
        wf[l][f][ch] = pack8(t);
      }

  const fx4 zacc = {0.f, 0.f, 0.f, 0.f};

  for (int i = 0; i < 8; ++i) {
    const int v = gw * 8 + i;
    float chmax0 = 0.f;
    float vmaxv  = 0.f;

    for (int h = 0; h < 2; ++h) {
      const int ptbase = v * 32 + h * 16;
      const float m = vmask[ptbase + p];
      float x2r[16];

      {
        const float* xrow = voxels + (size_t)(ptbase + p) * CIN;
        float t[8];
#pragma unroll
        for (int j = 0; j < 8; ++j) {
          int c = 8 * q + j;
          t[j] = (c < CIN) ? xrow[c] : 0.f;
        }
        short8_t bfrag = pack8(t);
        fx4 acc[4];
#pragma unroll
        for (int f = 0; f < 4; ++f)
          acc[f] = __builtin_amdgcn_mfma_f32_16x16x32_bf16(w1f[f], bfrag, zacc, 0, 0, 0);

        float s1 = 0.f, s2 = 0.f;
#pragma unroll
        for (int f = 0; f < 4; ++f)
#pragma unroll
          for (int r = 0; r < 4; ++r) { float x = acc[f][r]; s1 += x; s2 = fmaf(x, x, s2); }
        s1 += __shfl_xor(s1, 16); s1 += __shfl_xor(s1, 32);
        s2 += __shfl_xor(s2, 16); s2 += __shfl_xor(s2, 32);
        float mean = s1 * (1.f / 64.f);
        float rstd = rsqrtf(fmaf(-mean, mean, s2 * (1.f / 64.f)) + EPS);
#pragma unroll
        for (int f = 0; f < 4; ++f) {
          float4 gv = *(const float4*)(g1 + 4 * q + 16 * f);
          float4 bv = *(const float4*)(b1 + 4 * q + 16 * f);
          float go[4] = {gv.x, gv.y, gv.z, gv.w};
          float bo[4] = {bv.x, bv.y, bv.z, bv.w};
          short4_t s4;
#pragma unroll
          for (int r = 0; r < 4; ++r) {
            float t1 = fmaf((acc[f][r] - mean) * rstd, go[r], bo[r]);
            s4[r] = f2bf(mish(t1));
          }
          *(short4_t*)&mybuf[p * 72 + 4 * q + 16 * f] = s4;
        }
      }

#pragma unroll 1
      for (int l = 0; l < 3; ++l) {
        short8_t bf0 = *(short8_t*)&mybuf[p * 72 + 8 * q];
        short8_t bf1 = *(short8_t*)&mybuf[p * 72 + 8 * q + 32];
        fx4 acc[4];
#pragma unroll
        for (int f = 0; f < 4; ++f) {
          acc[f] = __builtin_amdgcn_mfma_f32_16x16x32_bf16(wf[l][f][0], bf0, zacc, 0, 0, 0);
          acc[f] = __builtin_amdgcn_mfma_f32_16x16x32_bf16(wf[l][f][1], bf1, acc[f], 0, 0, 0);
        }
        float s1 = 0.f, s2 = 0.f;
#pragma unroll
        for (int f = 0; f < 4; ++f)
#pragma unroll
          for (int r = 0; r < 4; ++r) { float x = acc[f][r]; s1 += x; s2 = fmaf(x, x, s2); }
        s1 += __shfl_xor(s1, 16); s1 += __shfl_xor(s1, 32);
        s2 += __shfl_xor(s2, 16); s2 += __shfl_xor(s2, 32);
        float mean = s1 * (1.f / 64.f);
        float rstd = rsqrtf(fmaf(-mean, mean, s2 * (1.f / 64.f)) + EPS);

        const float* gp = (l == 0) ? g2 : (l == 1) ? g3 : g4;
        const float* bp = (l == 0) ? b2 : (l == 1) ? b3 : b4;
#pragma unroll
        for (int f = 0; f < 4; ++f) {
          float4 gv = *(const float4*)(gp + 4 * q + 16 * f);
          float4 bv = *(const float4*)(bp + 4 * q + 16 * f);
          float go[4] = {gv.x, gv.y, gv.z, gv.w};
          float bo[4] = {bv.x, bv.y, bv.z, bv.w};
          if (l == 0) {
            short4_t s4;
#pragma unroll
            for (int r = 0; r < 4; ++r) {
              float t1 = fmaf((acc[f][r] - mean) * rstd, go[r], bo[r]);
              float a  = mish(t1) * m;
              x2r[f * 4 + r] = a;
              s4[r] = f2bf(a);
            }
            *(short4_t*)&mybuf[p * 72 + 4 * q + 16 * f] = s4;
          } else if (l == 1) {
            short4_t s4;
#pragma unroll
            for (int r = 0; r < 4; ++r) {
              float t1 = fmaf((acc[f][r] - mean) * rstd, go[r], bo[r]);
              s4[r] = f2bf(mish(t1));
            }
            *(short4_t*)&mybuf[p * 72 + 4 * q + 16 * f] = s4;
          } else {
            fx4 xf;
#pragma unroll
            for (int r = 0; r < 4; ++r) {
              float t1 = fmaf((acc[f][r] - mean) * rstd, go[r], bo[r]);
              xf[r] = fmaf(mish(t1), m, x2r[f * 4 + r]);
            }
            *(fx4*)&mymax[p * 68 + 4 * q + 16 * f] = xf;
          }
        }
      }

      float mx = -3.4e38f;
#pragma unroll
      for (int pp = 0; pp < 16; ++pp) mx = fmaxf(mx, mymax[pp * 68 + lane]);
      if (h == 0) chmax0 = mx; else vmaxv = fmaxf(chmax0, mx);
    }

    voxelwise[v * 64 + lane] = vmaxv;
  }
}

// ---------------------------------------------------------------------------
// Kernel 2: bfe1 + bfe2a + bfe2b via MFMA, split-precision (3-term).
// Block = 8 cells x 4 waves.  4 stages; at stage j wave w runs group 4j+w.
// Gather: each wave stages 2 cells' 16-ch slice into LDS (bf16 hi/lo,
// transposed [ch][v] via in-register 4x4 shuffle transpose).
// Dynamic LDS layout (shorts):
//   xh [8 cells][1288]            (ch-stride 80, cell-pad 8)
//   xl [8 cells][1288]
//   act[w][hl][16 rows][72]       (bfe1-out -> bfe2a B roundtrip, wave-private)
//   h2 [w][hl][16 rows][40]       (bfe2a-out concat -> bfe2b B, wave-private)
// ---------------------------------------------------------------------------
constexpr int XS_CH   = 80;            // shorts per ch row
constexpr int XS_CELL = 16 * 80 + 8;   // 1288 shorts per cell (16B-aligned)
constexpr int XH_OFF  = 0;
constexpr int XL_OFF  = 8 * XS_CELL;               // 10304
constexpr int ACT_OFF = 2 * 8 * XS_CELL;           // 20608
constexpr int ACT_WS  = 16 * 72;                   // per (w,hl): 1152
constexpr int H2_OFF  = ACT_OFF + 8 * ACT_WS;      // 29824
constexpr int H2_WS   = 16 * 40;                   // per (w,hl): 640
constexpr int SMEM_SHORTS = H2_OFF + 8 * H2_WS;    // 34944 shorts = 69888 B

__global__ __launch_bounds__(256, 2) void bfe12_mfma_kernel(
    const float* __restrict__ voxelwise, const int* __restrict__ bevsidx,
    const float* __restrict__ bevmask,
    const short* __restrict__ w1h, const short* __restrict__ w1l,
    const float* __restrict__ g1, const float* __restrict__ b1,
    const short* __restrict__ w2ah, const short* __restrict__ w2al,
    const float* __restrict__ g2a, const float* __restrict__ b2a,
    const short* __restrict__ w2bh, const short* __restrict__ w2bl,
    const float* __restrict__ g2b, const float* __restrict__ b2b,
    float* __restrict__ x17buf)
{
  extern __shared__ short sm[];

  const int tid  = threadIdx.x;
  const int lane = tid & 63;
  const int w    = tid >> 6;
  const int r15  = lane & 15;       // B-row / D-col index
  const int q    = lane >> 4;       // quad
  const int cellbase = blockIdx.x * 8;

  // gather lane decomposition
  const int chq   = lane & 3;
  const int v_loc = (lane >> 2) & 3;
  const int vblk  = lane >> 4;      // 0..3
  const int bit0  = v_loc & 1, bit1 = v_loc >> 1;

  // hoist gather indices: wave w gathers cells {2w, 2w+1}
  int idxr[2][4];
#pragma unroll
  for (int cc = 0; cc < 2; ++cc)
#pragma unroll
    for (int vb = 0; vb < 4; ++vb) {
      int v = 16 * vb + 4 * vblk + v_loc;
      idxr[cc][vb] = bevsidx[(cellbase + 2 * w + cc) * 64 + v];
    }

  // zero h2 pad rows (8..15) for both hi/lo — wave-private, done once
  {
    short* h2h = &sm[H2_OFF + (w * 2 + 0) * H2_WS];
    short* h2l = &sm[H2_OFF + (w * 2 + 1) * H2_WS];
    for (int i = lane; i < 320; i += 64) { h2h[320 + i] = 0; h2l[320 + i] = 0; }
  }

  const fx4 zacc = {0.f, 0.f, 0.f, 0.f};
  short* acth = &sm[ACT_OFF + (w * 2 + 0) * ACT_WS];
  short* actl = &sm[ACT_OFF + (w * 2 + 1) * ACT_WS];
  short* h2h  = &sm[H2_OFF + (w * 2 + 0) * H2_WS];
  short* h2l  = &sm[H2_OFF + (w * 2 + 1) * H2_WS];

#pragma unroll 1
  for (int j = 0; j < 4; ++j) {
    const int g = 4 * j + w;    // this wave's group this stage

    __syncthreads();   // prior stage's xbuf reads complete

    // ---- gather 16-ch slice (ch = 16j .. 16j+15) of my 2 cells ----
#pragma unroll
    for (int cc = 0; cc < 2; ++cc) {
#pragma unroll
      for (int vb = 0; vb < 4; ++vb) {
        const float* src = voxelwise + (size_t)idxr[cc][vb] * 64 + 16 * j + 4 * chq;
        float4 f4 = *(const float4*)src;
        float a0 = f4.x, a1 = f4.y, a2 = f4.z, a3 = f4.w;
        // 4x4 transpose across lanes {L, L^4, L^8, L^12}
        float gv0 = bit0 ? a0 : a1, gv1 = bit0 ? a2 : a3;
        float r0 = __shfl_xor(gv0, 4), r1 = __shfl_xor(gv1, 4);
        float c0 = bit0 ? r0 : a0, c1 = bit0 ? a1 : r0;
        float c2 = bit0 ? r1 : a2, c3 = bit0 ? a3 : r1;
        float h0 = bit1 ? c0 : c2, h1 = bit1 ? c1 : c3;
        float s0 = __shfl_xor(h0, 8), s1 = __shfl_xor(h1, 8);
        float d0 = bit1 ? s0 : c0, d1 = bit1 ? s1 : c1;
        float d2 = bit1 ? c2 : s0, d3 = bit1 ? c3 : s1;
        // lane now holds ch_loc = 4*chq + v_loc, v = 16vb+4vblk+(0..3)
        float dv[4] = {d0, d1, d2, d3};
        short4_t hi4, lo4;
#pragma unroll
        for (int r = 0; r < 4; ++r) {
          short h = f2bf(dv[r]);
          hi4[r] = h; lo4[r] = f2bf(dv[r] - bf2f(h));
        }
        int addr = (2 * w + cc) * XS_CELL + (4 * chq + v_loc) * XS_CH + 16 * vb + 4 * vblk;
        *(short4_t*)&sm[XH_OFF + addr] = hi4;
        *(short4_t*)&sm[XL_OFF + addr] = lo4;
      }
    }

    __syncthreads();   // xbuf slice ready for all waves

    // ---- A-frags for group g (global, L2-hot) ----
    short8_t W1hf[2][4], W1lf[2][4];
#pragma unroll
    for (int c = 0; c < 2; ++c)
#pragma unroll
      for (int f = 0; f < 4; ++f) {
        int off = (g * 64 + r15 + 16 * f) * 64 + 32 * c + 8 * q;
        W1hf[c][f] = *(const short8_t*)&w1h[off];
        W1lf[c][f] = *(const short8_t*)&w1l[off];
      }
    short8_t W2ahf[2], W2alf[2];
#pragma unroll
    for (int c = 0; c < 2; ++c) {
      int off = (g * 16 + r15) * 64 + 32 * c + 8 * q;
      W2ahf[c] = *(const short8_t*)&w2ah[off];
      W2alf[c] = *(const short8_t*)&w2al[off];
    }
    short8_t W2bhf, W2blf;
    {
      int off = (g * 16 + r15) * 32 + 8 * q;
      W2bhf = *(const short8_t*)&w2bh[off];
      W2blf = *(const short8_t*)&w2bl[off];
    }

    // ---- 2 tiles of 4 cells ----
#pragma unroll 1
    for (int t = 0; t < 2; ++t) {
      const int cl = r15 >> 2, p = r15 & 3;
      const int cell_loc = 4 * t + cl;
      const float bm = bevmask[cellbase + cell_loc];

      // bfe1: B-frags from xbuf
      int xaddr = cell_loc * XS_CELL + (4 * w + p) * XS_CH;
      short8_t xh0 = *(short8_t*)&sm[XH_OFF + xaddr + 8 * q];
      short8_t xh1 = *(short8_t*)&sm[XH_OFF + xaddr + 32 + 8 * q];
      short8_t xl0 = *(short8_t*)&sm[XL_OFF + xaddr + 8 * q];
      short8_t xl1 = *(short8_t*)&sm[XL_OFF + xaddr + 32 + 8 * q];

      fx4 acc[4];
#pragma unroll
      for (int f = 0; f < 4; ++f) {
        fx4 a = __builtin_amdgcn_mfma_f32_16x16x32_bf16(W1hf[0][f], xh0, zacc, 0, 0, 0);
        a = __builtin_amdgcn_mfma_f32_16x16x32_bf16(W1hf[0][f], xl0, a, 0, 0, 0);
        a = __builtin_amdgcn_mfma_f32_16x16x32_bf16(W1lf[0][f], xh0, a, 0, 0, 0);
        a = __builtin_amdgcn_mfma_f32_16x16x32_bf16(W1hf[1][f], xh1, a, 0, 0, 0);
        a = __builtin_amdgcn_mfma_f32_16x16x32_bf16(W1hf[1][f], xl1, a, 0, 0, 0);
        a = __builtin_amdgcn_mfma_f32_16x16x32_bf16(W1lf[1][f], xh1, a, 0, 0, 0);
        acc[f] = a;
      }

      // LN over 64 outputs of my row (col r15)
      float s1 = 0.f, s2 = 0.f;
#pragma unroll
      for (int f = 0; f < 4; ++f)
#pragma unroll
        for (int r = 0; r < 4; ++r) { float x = acc[f][r]; s1 += x; s2 = fmaf(x, x, s2); }
      s1 += __shfl_xor(s1, 16); s1 += __shfl_xor(s1, 32);
      s2 += __shfl_xor(s2, 16); s2 += __shfl_xor(s2, 32);
      float mean = s1 * (1.f / 64.f);
      float rstd = rsqrtf(fmaf(-mean, mean, s2 * (1.f / 64.f)) + EPS);

#pragma unroll
      for (int f = 0; f < 4; ++f) {
        float4 gv = *(const float4*)(g1 + g * 64 + 16 * f + 4 * q);
        float4 bv = *(const float4*)(b1 + g * 64 + 16 * f + 4 * q);
        float go[4] = {gv.x, gv.y, gv.z, gv.w};
        float bo[4] = {bv.x, bv.y, bv.z, bv.w};
        short4_t hi4, lo4;
#pragma unroll
        for (int r = 0; r < 4; ++r) {
          float t1 = fmaf((acc[f][r] - mean) * rstd, go[r], bo[r]);
          float a  = mish(t1) * bm;
          short h = f2bf(a);
          hi4[r] = h; lo4[r] = f2bf(a - bf2f(h));
        }
        *(short4_t*)&acth[r15 * 72 + 16 * f + 4 * q] = hi4;
        *(short4_t*)&actl[r15 * 72 + 16 * f + 4 * q] = lo4;
      }

      // bfe2a: B from actbuf (same-wave roundtrip)
      short8_t ah0 = *(short8_t*)&acth[r15 * 72 + 8 * q];
      short8_t ah1 = *(short8_t*)&acth[r15 * 72 + 32 + 8 * q];
      short8_t al0 = *(short8_t*)&actl[r15 * 72 + 8 * q];
      short8_t al1 = *(short8_t*)&actl[r15 * 72 + 32 + 8 * q];
      fx4 a2 = __builtin_amdgcn_mfma_f32_16x16x32_bf16(W2ahf[0], ah0, zacc, 0, 0, 0);
      a2 = __builtin_amdgcn_mfma_f32_16x16x32_bf16(W2ahf[0], al0, a2, 0, 0, 0);
      a2 = __builtin_amdgcn_mfma_f32_16x16x32_bf16(W2alf[0], ah0, a2, 0, 0, 0);
      a2 = __builtin_amdgcn_mfma_f32_16x16x32_bf16(W2ahf[1], ah1, a2, 0, 0, 0);
      a2 = __builtin_amdgcn_mfma_f32_16x16x32_bf16(W2ahf[1], al1, a2, 0, 0, 0);
      a2 = __builtin_amdgcn_mfma_f32_16x16x32_bf16(W2alf[1], ah1, a2, 0, 0, 0);

      // LN over 8 (rows 4q+r, valid q<2; rows 8..15 are exact zeros)
      float sa = a2[0] + a2[1] + a2[2] + a2[3];
      float sb = fmaf(a2[0], a2[0], fmaf(a2[1], a2[1], fmaf(a2[2], a2[2], a2[3] * a2[3])));
      sa += __shfl_xor(sa, 16); sb += __shfl_xor(sb, 16);
      if (q < 2) {
        float mean2 = sa * 0.125f;
        float rstd2 = rsqrtf(fmaf(-mean2, mean2, sb * 0.125f) + EPS);
        float4 gv = *(const float4*)(g2a + g * 8 + 4 * q);
        float4 bv = *(const float4*)(b2a + g * 8 + 4 * q);
        float go[4] = {gv.x, gv.y, gv.z, gv.w};
        float bo[4] = {bv.x, bv.y, bv.z, bv.w};
        short4_t hi4, lo4;
#pragma unroll
        for (int r = 0; r < 4; ++r) {
          float t1 = fmaf((a2[r] - mean2) * rstd2, go[r], bo[r]);
          float v  = mish(t1);
          short h = f2bf(v);
          hi4[r] = h; lo4[r] = f2bf(v - bf2f(h));
        }
        *(short4_t*)&h2h[cell_loc * 40 + p * 8 + 4 * q] = hi4;
        *(short4_t*)&h2l[cell_loc * 40 + p * 8 + 4 * q] = lo4;
      }
    }

    // ---- bfe2b: rows = 8 cells (+8 zero pad), K=32 ----
    {
      short8_t bh = *(short8_t*)&h2h[r15 * 40 + 8 * q];
      short8_t bl = *(short8_t*)&h2l[r15 * 40 + 8 * q];
      fx4 a3 = __builtin_amdgcn_mfma_f32_16x16x32_bf16(W2bhf, bh, zacc, 0, 0, 0);
      a3 = __builtin_amdgcn_mfma_f32_16x16x32_bf16(W2bhf, bl, a3, 0, 0, 0);
      a3 = __builtin_amdgcn_mfma_f32_16x16x32_bf16(W2blf, bh, a3, 0, 0, 0);

      float sa = a3[0] + a3[1] + a3[2] + a3[3];
      float sb = fmaf(a3[0], a3[0], fmaf(a3[1], a3[1], fmaf(a3[2], a3[2], a3[3] * a3[3])));
      sa += __shfl_xor(sa, 16); sb += __shfl_xor(sb, 16);
      if (q < 2 && r15 < 8) {
        float mean3 = sa * 0.125f;
        float rstd3 = rsqrtf(fmaf(-mean3, mean3, sb * 0.125f) + EPS);
        float4 gv = *(const float4*)(g2b + g * 8 + 4 * q);
        float4 bv = *(const float4*)(b2b + g * 8 + 4 * q);
        float go[4] = {gv.x, gv.y, gv.z, gv.w};
        float bo[4] = {bv.x, bv.y, bv.z, bv.w};
        float4 outv;
        float* op = &outv.x;
#pragma unroll
        for (int r = 0; r < 4; ++r) {
          float t1 = fmaf((a3[r] - mean3) * rstd3, go[r], bo[r]);
          op[r] = mish(t1);
        }
        *(float4*)&x17buf[(size_t)(cellbase + r15) * 128 + g * 8 + 4 * q] = outv;
      }
    }
  }
}

// ---------------------------------------------------------------------------
// Kernel 3: bfe3 twice + residual + scatter (unchanged fp32 this round)
// ---------------------------------------------------------------------------
__global__ __launch_bounds__(256) void bfe3_kernel(
    const float* __restrict__ x17buf, const int* __restrict__ bevcoors,
    const float* __restrict__ W3, const float* __restrict__ g3, const float* __restrict__ b3,
    float* __restrict__ out)
{
  extern __shared__ float smem[];
  float* ylds   = smem;
  float* x18lds = smem + 64 * 129;
  float* ps1    = smem + 2 * 64 * 129;
  float* ps2    = ps1 + 4 * 64;

  const int tid  = threadIdx.x;
  const int lane = tid & 63;
  const int w    = tid >> 6;
  const int cell = blockIdx.x * 64 + lane;

  float xv[128];
#pragma unroll
  for (int c = 0; c < 128; ++c) xv[c] = x17buf[cell * 128 + c];

  float s1 = 0.f, s2 = 0.f;
#pragma unroll 1
  for (int i = 0; i < 32; ++i) {
    const int o = 32 * w + i;
    const float* wr = &W3[o * 128];
    float acc = 0.f;
#pragma unroll
    for (int c = 0; c < 128; ++c) acc = fmaf(xv[c], wr[c], acc);
    ylds[lane * 129 + o] = acc; s1 += acc; s2 = fmaf(acc, acc, s2);
  }
  ps1[w * 64 + lane] = s1; ps2[w * 64 + lane] = s2;
  __syncthreads();
  {
    float S1 = ps1[lane] + ps1[64 + lane] + ps1[128 + lane] + ps1[192 + lane];
    float S2 = ps2[lane] + ps2[64 + lane] + ps2[128 + lane] + ps2[192 + lane];
    float mean = S1 * (1.f / 128.f);
    float var  = fmaf(-mean, mean, S2 * (1.f / 128.f));
    float r = rsqrtf(var + EPS);
#pragma unroll 1
    for (int i = 0; i < 32; ++i) {
      const int o = 32 * w + i;
      x18lds[lane * 129 + o] =
          mish(fmaf((ylds[lane * 129 + o] - mean) * r, g3[o], b3[o]));
    }
  }
  __syncthreads();

#pragma unroll
  for (int c = 0; c < 128; ++c) xv[c] = x18lds[lane * 129 + c];

  s1 = 0.f; s2 = 0.f;
#pragma unroll 1
  for (int i = 0; i < 32; ++i) {
    const int o = 32 * w + i;
    const float* wr = &W3[o * 128];
    float acc = 0.f;
#pragma unroll
    for (int c = 0; c < 128; ++c) acc = fmaf(xv[c], wr[c], acc);
    ylds[lane * 129 + o] = acc; s1 += acc; s2 = fmaf(acc, acc, s2);
  }
  ps1[w * 64 + lane] = s1; ps2[w * 64 + lane] = s2;
  __syncthreads();
  {
    float S1 = ps1[lane] + ps1[64 + lane] + ps1[128 + lane] + ps1[192 + lane];
    float S2 = ps2[lane] + ps2[64 + lane] + ps2[128 + lane] + ps2[192 + lane];
    float mean = S1 * (1.f / 128.f);
    float var  = fmaf(-mean, mean, S2 * (1.f / 128.f));
    float r = rsqrtf(var + EPS);
    const int hq = bevcoors[cell * 2 + 0];
    const int wq = bevcoors[cell * 2 + 1];
#pragma unroll 1
    for (int i = 0; i < 32; ++i) {
      const int o = 32 * w + i;
      float val = mish(fmaf((ylds[lane * 129 + o] - mean) * r, g3[o], b3[o]))
                  + x17buf[cell * 128 + o];
      out[o * HW + wq * BEV_H + hq] = val;
    }
  }
}

// ---------------------------------------------------------------------------
extern "C" void kernel_launch(void* const* d_in, const int* in_sizes, int n_in,
                              void* d_out, int out_size, void* d_ws, size_t ws_size,
                              hipStream_t stream) {
  const float* voxels   = (const float*)d_in[0];
  const float* vmask    = (const float*)d_in[1];
  const int*   bevsidx  = (const int*)d_in[2];
  const int*   bevcoors = (const int*)d_in[3];
  const float* bevmask  = (const float*)d_in[4];
  const float* vfe1_W = (const float*)d_in[5];
  const float* vfe1_g = (const float*)d_in[6];
  const float* vfe1_b = (const float*)d_in[7];
  const float* vfe2_W = (const float*)d_in[8];
  const float* vfe2_g = (const float*)d_in[9];
  const float* vfe2_b = (const float*)d_in[10];
  const float* vfe3_W = (const float*)d_in[11];
  const float* vfe3_g = (const float*)d_in[12];
  const float* vfe3_b = (const float*)d_in[13];
  const float* vfe4_W = (const float*)d_in[14];
  const float* vfe4_g = (const float*)d_in[15];
  const float* vfe4_b = (const float*)d_in[16];
  const float* bfe1_W  = (const float*)d_in[17];
  const float* bfe1_g  = (const float*)d_in[18];
  const float* bfe1_b  = (const float*)d_in[19];
  const float* bfe2a_W = (const float*)d_in[20];
  const float* bfe2a_g = (const float*)d_in[21];
  const float* bfe2a_b = (const float*)d_in[22];
  const float* bfe2b_W = (const float*)d_in[23];
  const float* bfe2b_g = (const float*)d_in[24];
  const float* bfe2b_b = (const float*)d_in[25];
  const float* bfe3_W  = (const float*)d_in[26];
  const float* bfe3_g  = (const float*)d_in[27];
  const float* bfe3_b  = (const float*)d_in[28];

  float* voxelwise = (float*)d_ws;                    // NV*CV floats
  float* x17buf    = voxelwise + NV * CV;             // NB*128 floats
  short* wbase     = (short*)(x17buf + NB * 128);     // bf16 weight area
  short* w1h  = wbase;                                // 65536
  short* w1l  = w1h + 65536;
  short* w2ah = w1l + 65536;                          // 16384
  short* w2al = w2ah + 16384;
  short* w2bh = w2al + 16384;                         // 8192
  short* w2bl = w2bh + 8192;
  float* out = (float*)d_out;

  hipMemsetAsync(d_out, 0, (size_t)out_size * sizeof(float), stream);

  pack_weights_kernel<<<(90112 + 255) / 256, 256, 0, stream>>>(
      bfe1_W, bfe2a_W, bfe2b_W, w1h, w1l, w2ah, w2al, w2bh, w2bl);

  vfe_mfma_kernel<<<500, 256, 0, stream>>>(
      voxels, vmask,
      vfe1_W, vfe1_g, vfe1_b, vfe2_W, vfe2_g, vfe2_b,
      vfe3_W, vfe3_g, vfe3_b, vfe4_W, vfe4_g, vfe4_b,
      voxelwise);

  bfe12_mfma_kernel<<<NB / 8, 256, SMEM_SHORTS * sizeof(short), stream>>>(
      voxelwise, bevsidx, bevmask,
      w1h, w1l, bfe1_g, bfe1_b,
      w2ah, w2al, bfe2a_g, bfe2a_b,
      w2bh, w2bl, bfe2b_g, bfe2b_b,
      x17buf);

  size_t shC = (2 * 64 * 129 + 8 * 64) * sizeof(float);
  bfe3_kernel<<<NB / 64, 256, shC, stream>>>(
      x17buf, bevcoors, bfe3_W, bfe3_g, bfe3_b, out);
}

// Round 5
// 549.719 us; speedup vs baseline: 2.0625x; 1.3165x over previous
//
#include <hip/hip_runtime.h>
#include <math.h>

// Problem constants (from reference setup_inputs)
constexpr int NV  = 16000;   // voxels
constexpr int P   = 32;      // points per voxel
constexpr int CIN = 10;      // input channels
constexpr int CV  = 64;      // voxel feature channels
constexpr int NB  = 16000;   // BEV cells
constexpr int BEV_H = 496, BEV_W = 432;
constexpr int HW = BEV_H * BEV_W;  // 214272
constexpr float EPS = 1e-5f;

typedef __attribute__((ext_vector_type(8))) short short8_t;  // 8 bf16 (4 VGPR)
typedef __attribute__((ext_vector_type(4))) short short4_t;  // 4 bf16
typedef __attribute__((ext_vector_type(4))) float fx4;       // MFMA C/D frag

__device__ __forceinline__ float mish(float x) {
  float e = __expf(fminf(x, 15.f));
  float n = fmaf(e, e, 2.f * e);
  return x * __fdividef(n, n + 2.f);
}

__device__ __forceinline__ short f2bf(float f) {
  unsigned u = __builtin_bit_cast(unsigned, f);
  u += 0x7FFF + ((u >> 16) & 1);
  return (short)(u >> 16);
}
__device__ __forceinline__ float bf2f(short s) {
  unsigned u = ((unsigned)(unsigned short)s) << 16;
  return __builtin_bit_cast(float, u);
}
__device__ __forceinline__ short8_t pack8(const float* t) {
  short8_t s;
#pragma unroll
  for (int j = 0; j < 8; ++j) s[j] = f2bf(t[j]);
  return s;
}

// ---------------------------------------------------------------------------
// Prologue: split bfe weights into bf16 hi/lo. W2a/W2b o-padded to 16.
// Also splits bfe3_W (128x128).
// ---------------------------------------------------------------------------
__global__ __launch_bounds__(256) void pack_weights_kernel(
    const float* __restrict__ W1, const float* __restrict__ W2a,
    const float* __restrict__ W2b, const float* __restrict__ W3,
    short* __restrict__ w1h, short* __restrict__ w1l,
    short* __restrict__ w2ah, short* __restrict__ w2al,
    short* __restrict__ w2bh, short* __restrict__ w2bl,
    short* __restrict__ w3h, short* __restrict__ w3l)
{
  int i = blockIdx.x * 256 + threadIdx.x;
  if (i < 65536) {
    float v = W1[i];
    short h = f2bf(v);
    w1h[i] = h; w1l[i] = f2bf(v - bf2f(h));
  } else if (i < 81920) {
    int j = i - 65536;
    int g = j >> 10, o = (j >> 6) & 15, c = j & 63;
    float v = (o < 8) ? W2a[(g * 8 + o) * 64 + c] : 0.f;
    short h = f2bf(v);
    w2ah[j] = h; w2al[j] = f2bf(v - bf2f(h));
  } else if (i < 90112) {
    int k = i - 81920;
    int g = k >> 9, o = (k >> 5) & 15, c = k & 31;
    float v = (o < 8) ? W2b[(g * 8 + o) * 32 + c] : 0.f;
    short h = f2bf(v);
    w2bh[k] = h; w2bl[k] = f2bf(v - bf2f(h));
  } else if (i < 106496) {
    int j = i - 90112;
    float v = W3[j];
    short h = f2bf(v);
    w3h[j] = h; w3l[j] = f2bf(v - bf2f(h));
  }
}

// ---------------------------------------------------------------------------
// VFE v3: weight A-frags in block-shared LDS; act slab wave-private bf16.
// Max-over-points epilogue is PURE-REGISTER: butterfly max over the 16
// points of a half leaves the max in every lane of each 16-lane group;
// a 16-step __shfl + compile-time select transposes (group,frag) -> channel.
// No LDS aliasing, no divergent LDS writes.
// Grid: 1000 blocks x 4 waves, 4 voxels per wave.
// ---------------------------------------------------------------------------
__global__ __launch_bounds__(256, 3) void vfe_mfma3_kernel(
    const float* __restrict__ voxels, const float* __restrict__ vmask,
    const float* __restrict__ W1, const float* __restrict__ g1, const float* __restrict__ b1,
    const float* __restrict__ W2, const float* __restrict__ g2, const float* __restrict__ b2,
    const float* __restrict__ W3, const float* __restrict__ g3, const float* __restrict__ b3,
    const float* __restrict__ W4, const float* __restrict__ g4, const float* __restrict__ b4,
    float* __restrict__ voxelwise)
{
  __shared__ short wlds[28 * 512];     // 28,672 B: shared A-frags
  __shared__ short actb[4][16 * 72];   // 9,216 B: wave-private act slabs

  const int tid  = threadIdx.x;
  const int lane = tid & 63;
  const int w    = tid >> 6;
  const int p    = lane & 15;
  const int q    = lane >> 4;
  const int gw   = blockIdx.x * 4 + w;

  // ---- stage weight A-frags into LDS (cooperative) ----
  for (int s = w; s < 28; s += 4) {
    float t[8];
    if (s < 4) {
      const int f = s;
#pragma unroll
      for (int j = 0; j < 8; ++j) {
        int c = 8 * q + j;
        t[j] = (c < CIN) ? W1[(p + 16 * f) * CIN + c] : 0.f;
      }
    } else {
      const int l = (s - 4) >> 3, rem = (s - 4) & 7, ch = rem >> 2, f = rem & 3;
      const float* Wl = (l == 0) ? W2 : (l == 1) ? W3 : W4;
      const float* src = Wl + (p + 16 * f) * CV + 32 * ch + 8 * q;
#pragma unroll
      for (int j = 0; j < 8; ++j) t[j] = src[j];
    }
    *(short8_t*)&wlds[s * 512 + lane * 8] = pack8(t);
  }
  __syncthreads();

  short* mybuf = &actb[w][0];
  const fx4 zacc = {0.f, 0.f, 0.f, 0.f};
  const int srcLane = ((lane >> 2) & 3) * 16;   // transpose source lane

  for (int i = 0; i < 4; ++i) {
    const int v = gw * 4 + i;
    float chmax0 = 0.f, vmaxv = 0.f;

    for (int h = 0; h < 2; ++h) {
      const int ptbase = v * 32 + h * 16;
      const float m = vmask[ptbase + p];
      float x2r[16];
      float vmax[4][4];   // layer-4 group-max values (set at l==2)

      // ---- layer 1 ----
      {
        const float* xrow = voxels + (size_t)(ptbase + p) * CIN;  // 8B-aligned
        float t[8] = {0.f, 0.f, 0.f, 0.f, 0.f, 0.f, 0.f, 0.f};
        if (q == 0) {
          float2 a = *(const float2*)(xrow + 0);
          float2 b = *(const float2*)(xrow + 2);
          float2 c = *(const float2*)(xrow + 4);
          float2 d = *(const float2*)(xrow + 6);
          t[0] = a.x; t[1] = a.y; t[2] = b.x; t[3] = b.y;
          t[4] = c.x; t[5] = c.y; t[6] = d.x; t[7] = d.y;
        } else if (q == 1) {
          float2 a = *(const float2*)(xrow + 8);
          t[0] = a.x; t[1] = a.y;
        }
        short8_t bfrag = pack8(t);
        fx4 acc[4];
#pragma unroll
        for (int f = 0; f < 4; ++f) {
          short8_t af = *(short8_t*)&wlds[f * 512 + lane * 8];
          acc[f] = __builtin_amdgcn_mfma_f32_16x16x32_bf16(af, bfrag, zacc, 0, 0, 0);
        }
        float s1 = 0.f, s2 = 0.f;
#pragma unroll
        for (int f = 0; f < 4; ++f)
#pragma unroll
          for (int r = 0; r < 4; ++r) { float x = acc[f][r]; s1 += x; s2 = fmaf(x, x, s2); }
        s1 += __shfl_xor(s1, 16); s1 += __shfl_xor(s1, 32);
        s2 += __shfl_xor(s2, 16); s2 += __shfl_xor(s2, 32);
        float mean = s1 * (1.f / 64.f);
        float rstd = rsqrtf(fmaf(-mean, mean, s2 * (1.f / 64.f)) + EPS);
#pragma unroll
        for (int f = 0; f < 4; ++f) {
          float4 gv = *(const float4*)(g1 + 4 * q + 16 * f);
          float4 bv = *(const float4*)(b1 + 4 * q + 16 * f);
          float go[4] = {gv.x, gv.y, gv.z, gv.w};
          float bo[4] = {bv.x, bv.y, bv.z, bv.w};
          short4_t s4;
#pragma unroll
          for (int r = 0; r < 4; ++r) {
            float t1 = fmaf((acc[f][r] - mean) * rstd, go[r], bo[r]);
            s4[r] = f2bf(mish(t1));
          }
          *(short4_t*)&mybuf[p * 72 + 4 * q + 16 * f] = s4;
        }
      }

      // ---- layers 2..4 ----
#pragma unroll 1
      for (int l = 0; l < 3; ++l) {
        short8_t bf0 = *(short8_t*)&mybuf[p * 72 + 8 * q];
        short8_t bf1 = *(short8_t*)&mybuf[p * 72 + 8 * q + 32];
        fx4 acc[4];
#pragma unroll
        for (int f = 0; f < 4; ++f) {
          short8_t a0 = *(short8_t*)&wlds[(4 + l * 8 + f) * 512 + lane * 8];
          short8_t a1 = *(short8_t*)&wlds[(4 + l * 8 + 4 + f) * 512 + lane * 8];
          fx4 a = __builtin_amdgcn_mfma_f32_16x16x32_bf16(a0, bf0, zacc, 0, 0, 0);
          acc[f] = __builtin_amdgcn_mfma_f32_16x16x32_bf16(a1, bf1, a, 0, 0, 0);
        }
        float s1 = 0.f, s2 = 0.f;
#pragma unroll
        for (int f = 0; f < 4; ++f)
#pragma unroll
          for (int r = 0; r < 4; ++r) { float x = acc[f][r]; s1 += x; s2 = fmaf(x, x, s2); }
        s1 += __shfl_xor(s1, 16); s1 += __shfl_xor(s1, 32);
        s2 += __shfl_xor(s2, 16); s2 += __shfl_xor(s2, 32);
        float mean = s1 * (1.f / 64.f);
        float rstd = rsqrtf(fmaf(-mean, mean, s2 * (1.f / 64.f)) + EPS);

        const float* gp = (l == 0) ? g2 : (l == 1) ? g3 : g4;
        const float* bp = (l == 0) ? b2 : (l == 1) ? b3 : b4;
#pragma unroll
        for (int f = 0; f < 4; ++f) {
          float4 gv = *(const float4*)(gp + 4 * q + 16 * f);
          float4 bv = *(const float4*)(bp + 4 * q + 16 * f);
          float go[4] = {gv.x, gv.y, gv.z, gv.w};
          float bo[4] = {bv.x, bv.y, bv.z, bv.w};
          if (l == 0) {            // layer 2: *mask, keep residual
            short4_t s4;
#pragma unroll
            for (int r = 0; r < 4; ++r) {
              float t1 = fmaf((acc[f][r] - mean) * rstd, go[r], bo[r]);
              float a  = mish(t1) * m;
              x2r[f * 4 + r] = a;
              s4[r] = f2bf(a);
            }
            *(short4_t*)&mybuf[p * 72 + 4 * q + 16 * f] = s4;
          } else if (l == 1) {     // layer 3
            short4_t s4;
#pragma unroll
            for (int r = 0; r < 4; ++r) {
              float t1 = fmaf((acc[f][r] - mean) * rstd, go[r], bo[r]);
              s4[r] = f2bf(mish(t1));
            }
            *(short4_t*)&mybuf[p * 72 + 4 * q + 16 * f] = s4;
          } else {                 // layer 4: *mask + residual, butterfly max over p
#pragma unroll
            for (int r = 0; r < 4; ++r) {
              float t1 = fmaf((acc[f][r] - mean) * rstd, go[r], bo[r]);
              float v0 = fmaf(mish(t1), m, x2r[f * 4 + r]);
              v0 = fmaxf(v0, __shfl_xor(v0, 1));
              v0 = fmaxf(v0, __shfl_xor(v0, 2));
              v0 = fmaxf(v0, __shfl_xor(v0, 4));
              v0 = fmaxf(v0, __shfl_xor(v0, 8));
              vmax[f][r] = v0;     // uniform within each 16-lane group
            }
          }
        }
      }

      // ---- register transpose: lane L wants channel L = 16f + 4q' + r ----
      float hm = 0.f;
#pragma unroll
      for (int f = 0; f < 4; ++f)
#pragma unroll
        for (int r = 0; r < 4; ++r) {
          float vsh = __shfl(vmax[f][r], srcLane);
          if (((lane >> 4) == f) && ((lane & 3) == r)) hm = vsh;
        }
      if (h == 0) chmax0 = hm; else vmaxv = fmaxf(chmax0, hm);
    }
    voxelwise[v * 64 + lane] = vmaxv;    // coalesced
  }
}

// ---------------------------------------------------------------------------
// Kernel 2: bfe1 + bfe2a + bfe2b via MFMA, split-precision (unchanged r3).
// ---------------------------------------------------------------------------
constexpr int XS_CH   = 80;
constexpr int XS_CELL = 16 * 80 + 8;
constexpr int XH_OFF  = 0;
constexpr int XL_OFF  = 8 * XS_CELL;
constexpr int ACT_OFF = 2 * 8 * XS_CELL;
constexpr int ACT_WS  = 16 * 72;
constexpr int H2_OFF  = ACT_OFF + 8 * ACT_WS;
constexpr int H2_WS   = 16 * 40;
constexpr int SMEM_SHORTS = H2_OFF + 8 * H2_WS;

__global__ __launch_bounds__(256, 2) void bfe12_mfma_kernel(
    const float* __restrict__ voxelwise, const int* __restrict__ bevsidx,
    const float* __restrict__ bevmask,
    const short* __restrict__ w1h, const short* __restrict__ w1l,
    const float* __restrict__ g1, const float* __restrict__ b1,
    const short* __restrict__ w2ah, const short* __restrict__ w2al,
    const float* __restrict__ g2a, const float* __restrict__ b2a,
    const short* __restrict__ w2bh, const short* __restrict__ w2bl,
    const float* __restrict__ g2b, const float* __restrict__ b2b,
    float* __restrict__ x17buf)
{
  extern __shared__ short sm[];

  const int tid  = threadIdx.x;
  const int lane = tid & 63;
  const int w    = tid >> 6;
  const int r15  = lane & 15;
  const int q    = lane >> 4;
  const int cellbase = blockIdx.x * 8;

  const int chq   = lane & 3;
  const int v_loc = (lane >> 2) & 3;
  const int vblk  = lane >> 4;
  const int bit0  = v_loc & 1, bit1 = v_loc >> 1;

  int idxr[2][4];
#pragma unroll
  for (int cc = 0; cc < 2; ++cc)
#pragma unroll
    for (int vb = 0; vb < 4; ++vb) {
      int v = 16 * vb + 4 * vblk + v_loc;
      idxr[cc][vb] = bevsidx[(cellbase + 2 * w + cc) * 64 + v];
    }

  {
    short* zh = &sm[H2_OFF + (w * 2 + 0) * H2_WS];
    short* zl = &sm[H2_OFF + (w * 2 + 1) * H2_WS];
    for (int i = lane; i < 320; i += 64) { zh[320 + i] = 0; zl[320 + i] = 0; }
  }

  const fx4 zacc = {0.f, 0.f, 0.f, 0.f};
  short* acth = &sm[ACT_OFF + (w * 2 + 0) * ACT_WS];
  short* actl = &sm[ACT_OFF + (w * 2 + 1) * ACT_WS];
  short* h2h  = &sm[H2_OFF + (w * 2 + 0) * H2_WS];
  short* h2l  = &sm[H2_OFF + (w * 2 + 1) * H2_WS];

#pragma unroll 1
  for (int j = 0; j < 4; ++j) {
    const int g = 4 * j + w;

    __syncthreads();

#pragma unroll
    for (int cc = 0; cc < 2; ++cc) {
#pragma unroll
      for (int vb = 0; vb < 4; ++vb) {
        const float* src = voxelwise + (size_t)idxr[cc][vb] * 64 + 16 * j + 4 * chq;
        float4 f4 = *(const float4*)src;
        float a0 = f4.x, a1 = f4.y, a2 = f4.z, a3 = f4.w;
        float gv0 = bit0 ? a0 : a1, gv1 = bit0 ? a2 : a3;
        float r0 = __shfl_xor(gv0, 4), r1 = __shfl_xor(gv1, 4);
        float c0 = bit0 ? r0 : a0, c1 = bit0 ? a1 : r0;
        float c2 = bit0 ? r1 : a2, c3 = bit0 ? a3 : r1;
        float h0 = bit1 ? c0 : c2, h1 = bit1 ? c1 : c3;
        float s0 = __shfl_xor(h0, 8), s1 = __shfl_xor(h1, 8);
        float d0 = bit1 ? s0 : c0, d1 = bit1 ? s1 : c1;
        float d2 = bit1 ? c2 : s0, d3 = bit1 ? c3 : s1;
        float dv[4] = {d0, d1, d2, d3};
        short4_t hi4, lo4;
#pragma unroll
        for (int r = 0; r < 4; ++r) {
          short h = f2bf(dv[r]);
          hi4[r] = h; lo4[r] = f2bf(dv[r] - bf2f(h));
        }
        int addr = (2 * w + cc) * XS_CELL + (4 * chq + v_loc) * XS_CH + 16 * vb + 4 * vblk;
        *(short4_t*)&sm[XH_OFF + addr] = hi4;
        *(short4_t*)&sm[XL_OFF + addr] = lo4;
      }
    }

    __syncthreads();

    short8_t W1hf[2][4], W1lf[2][4];
#pragma unroll
    for (int c = 0; c < 2; ++c)
#pragma unroll
      for (int f = 0; f < 4; ++f) {
        int off = (g * 64 + r15 + 16 * f) * 64 + 32 * c + 8 * q;
        W1hf[c][f] = *(const short8_t*)&w1h[off];
        W1lf[c][f] = *(const short8_t*)&w1l[off];
      }
    short8_t W2ahf[2], W2alf[2];
#pragma unroll
    for (int c = 0; c < 2; ++c) {
      int off = (g * 16 + r15) * 64 + 32 * c + 8 * q;
      W2ahf[c] = *(const short8_t*)&w2ah[off];
      W2alf[c] = *(const short8_t*)&w2al[off];
    }
    short8_t W2bhf, W2blf;
    {
      int off = (g * 16 + r15) * 32 + 8 * q;
      W2bhf = *(const short8_t*)&w2bh[off];
      W2blf = *(const short8_t*)&w2bl[off];
    }

#pragma unroll 1
    for (int t = 0; t < 2; ++t) {
      const int cl = r15 >> 2, p = r15 & 3;
      const int cell_loc = 4 * t + cl;
      const float bm = bevmask[cellbase + cell_loc];

      int xaddr = cell_loc * XS_CELL + (4 * w + p) * XS_CH;
      short8_t xh0 = *(short8_t*)&sm[XH_OFF + xaddr + 8 * q];
      short8_t xh1 = *(short8_t*)&sm[XH_OFF + xaddr + 32 + 8 * q];
      short8_t xl0 = *(short8_t*)&sm[XL_OFF + xaddr + 8 * q];
      short8_t xl1 = *(short8_t*)&sm[XL_OFF + xaddr + 32 + 8 * q];

      fx4 acc[4];
#pragma unroll
      for (int f = 0; f < 4; ++f) {
        fx4 a = __builtin_amdgcn_mfma_f32_16x16x32_bf16(W1hf[0][f], xh0, zacc, 0, 0, 0);
        a = __builtin_amdgcn_mfma_f32_16x16x32_bf16(W1hf[0][f], xl0, a, 0, 0, 0);
        a = __builtin_amdgcn_mfma_f32_16x16x32_bf16(W1lf[0][f], xh0, a, 0, 0, 0);
        a = __builtin_amdgcn_mfma_f32_16x16x32_bf16(W1hf[1][f], xh1, a, 0, 0, 0);
        a = __builtin_amdgcn_mfma_f32_16x16x32_bf16(W1hf[1][f], xl1, a, 0, 0, 0);
        a = __builtin_amdgcn_mfma_f32_16x16x32_bf16(W1lf[1][f], xh1, a, 0, 0, 0);
        acc[f] = a;
      }

      float s1 = 0.f, s2 = 0.f;
#pragma unroll
      for (int f = 0; f < 4; ++f)
#pragma unroll
        for (int r = 0; r < 4; ++r) { float x = acc[f][r]; s1 += x; s2 = fmaf(x, x, s2); }
      s1 += __shfl_xor(s1, 16); s1 += __shfl_xor(s1, 32);
      s2 += __shfl_xor(s2, 16); s2 += __shfl_xor(s2, 32);
      float mean = s1 * (1.f / 64.f);
      float rstd = rsqrtf(fmaf(-mean, mean, s2 * (1.f / 64.f)) + EPS);

#pragma unroll
      for (int f = 0; f < 4; ++f) {
        float4 gv = *(const float4*)(g1 + g * 64 + 16 * f + 4 * q);
        float4 bv = *(const float4*)(b1 + g * 64 + 16 * f + 4 * q);
        float go[4] = {gv.x, gv.y, gv.z, gv.w};
        float bo[4] = {bv.x, bv.y, bv.z, bv.w};
        short4_t hi4, lo4;
#pragma unroll
        for (int r = 0; r < 4; ++r) {
          float t1 = fmaf((acc[f][r] - mean) * rstd, go[r], bo[r]);
          float a  = mish(t1) * bm;
          short h = f2bf(a);
          hi4[r] = h; lo4[r] = f2bf(a - bf2f(h));
        }
        *(short4_t*)&acth[r15 * 72 + 16 * f + 4 * q] = hi4;
        *(short4_t*)&actl[r15 * 72 + 16 * f + 4 * q] = lo4;
      }

      short8_t ah0 = *(short8_t*)&acth[r15 * 72 + 8 * q];
      short8_t ah1 = *(short8_t*)&acth[r15 * 72 + 32 + 8 * q];
      short8_t al0 = *(short8_t*)&actl[r15 * 72 + 8 * q];
      short8_t al1 = *(short8_t*)&actl[r15 * 72 + 32 + 8 * q];
      fx4 a2 = __builtin_amdgcn_mfma_f32_16x16x32_bf16(W2ahf[0], ah0, zacc, 0, 0, 0);
      a2 = __builtin_amdgcn_mfma_f32_16x16x32_bf16(W2ahf[0], al0, a2, 0, 0, 0);
      a2 = __builtin_amdgcn_mfma_f32_16x16x32_bf16(W2alf[0], ah0, a2, 0, 0, 0);
      a2 = __builtin_amdgcn_mfma_f32_16x16x32_bf16(W2ahf[1], ah1, a2, 0, 0, 0);
      a2 = __builtin_amdgcn_mfma_f32_16x16x32_bf16(W2ahf[1], al1, a2, 0, 0, 0);
      a2 = __builtin_amdgcn_mfma_f32_16x16x32_bf16(W2alf[1], ah1, a2, 0, 0, 0);

      float sa = a2[0] + a2[1] + a2[2] + a2[3];
      float sb = fmaf(a2[0], a2[0], fmaf(a2[1], a2[1], fmaf(a2[2], a2[2], a2[3] * a2[3])));
      sa += __shfl_xor(sa, 16); sb += __shfl_xor(sb, 16);
      if (q < 2) {
        float mean2 = sa * 0.125f;
        float rstd2 = rsqrtf(fmaf(-mean2, mean2, sb * 0.125f) + EPS);
        float4 gv = *(const float4*)(g2a + g * 8 + 4 * q);
        float4 bv = *(const float4*)(b2a + g * 8 + 4 * q);
        float go[4] = {gv.x, gv.y, gv.z, gv.w};
        float bo[4] = {bv.x, bv.y, bv.z, bv.w};
        short4_t hi4, lo4;
#pragma unroll
        for (int r = 0; r < 4; ++r) {
          float t1 = fmaf((a2[r] - mean2) * rstd2, go[r], bo[r]);
          float v  = mish(t1);
          short h = f2bf(v);
          hi4[r] = h; lo4[r] = f2bf(v - bf2f(h));
        }
        *(short4_t*)&h2h[cell_loc * 40 + p * 8 + 4 * q] = hi4;
        *(short4_t*)&h2l[cell_loc * 40 + p * 8 + 4 * q] = lo4;
      }
    }

    {
      short8_t bh = *(short8_t*)&h2h[r15 * 40 + 8 * q];
      short8_t bl = *(short8_t*)&h2l[r15 * 40 + 8 * q];
      fx4 a3 = __builtin_amdgcn_mfma_f32_16x16x32_bf16(W2bhf, bh, zacc, 0, 0, 0);
      a3 = __builtin_amdgcn_mfma_f32_16x16x32_bf16(W2bhf, bl, a3, 0, 0, 0);
      a3 = __builtin_amdgcn_mfma_f32_16x16x32_bf16(W2blf, bh, a3, 0, 0, 0);

      float sa = a3[0] + a3[1] + a3[2] + a3[3];
      float sb = fmaf(a3[0], a3[0], fmaf(a3[1], a3[1], fmaf(a3[2], a3[2], a3[3] * a3[3])));
      sa += __shfl_xor(sa, 16); sb += __shfl_xor(sb, 16);
      if (q < 2 && r15 < 8) {
        float mean3 = sa * 0.125f;
        float rstd3 = rsqrtf(fmaf(-mean3, mean3, sb * 0.125f) + EPS);
        float4 gv = *(const float4*)(g2b + g * 8 + 4 * q);
        float4 bv = *(const float4*)(b2b + g * 8 + 4 * q);
        float go[4] = {gv.x, gv.y, gv.z, gv.w};
        float bo[4] = {bv.x, bv.y, bv.z, bv.w};
        float4 outv;
        float* op = &outv.x;
#pragma unroll
        for (int r = 0; r < 4; ++r) {
          float t1 = fmaf((a3[r] - mean3) * rstd3, go[r], bo[r]);
          op[r] = mish(t1);
        }
        *(float4*)&x17buf[(size_t)(cellbase + r15) * 128 + g * 8 + 4 * q] = outv;
      }
    }
  }
}

// ---------------------------------------------------------------------------
// Kernel 3: bfe3 twice + residual + scatter via MFMA (unchanged r4).
// ---------------------------------------------------------------------------
__global__ __launch_bounds__(256, 2) void bfe3_mfma_kernel(
    const float* __restrict__ x17buf, const int* __restrict__ bevcoors,
    const short* __restrict__ w3h, const short* __restrict__ w3l,
    const float* __restrict__ g3, const float* __restrict__ b3,
    float* __restrict__ out)
{
  __shared__ short x18h[4][16 * 136];
  __shared__ short x18l[4][16 * 136];

  const int tid  = threadIdx.x;
  const int lane = tid & 63;
  const int w    = tid >> 6;
  const int r15  = lane & 15;
  const int q    = lane >> 4;
  const int cell = blockIdx.x * 64 + w * 16 + r15;
  const float* xr = x17buf + (size_t)cell * 128;
  short* xh18 = &x18h[w][0];
  short* xl18 = &x18l[w][0];
  const fx4 zacc = {0.f, 0.f, 0.f, 0.f};

  short8_t xh[4], xl[4];
#pragma unroll
  for (int c = 0; c < 4; ++c) {
    const float* s = xr + 32 * c + 8 * q;
    float4 A = *(const float4*)s;
    float4 B = *(const float4*)(s + 4);
    float t[8] = {A.x, A.y, A.z, A.w, B.x, B.y, B.z, B.w};
    short8_t hi, lo;
#pragma unroll
    for (int jj = 0; jj < 8; ++jj) {
      short hh = f2bf(t[jj]);
      hi[jj] = hh; lo[jj] = f2bf(t[jj] - bf2f(hh));
    }
    xh[c] = hi; xl[c] = lo;
  }

  fx4 acc[8];
#pragma unroll
  for (int f = 0; f < 8; ++f) {
    fx4 a = zacc;
#pragma unroll
    for (int c = 0; c < 4; ++c) {
      int off = (16 * f + r15) * 128 + 32 * c + 8 * q;
      short8_t Ah = *(const short8_t*)&w3h[off];
      short8_t Al = *(const short8_t*)&w3l[off];
      a = __builtin_amdgcn_mfma_f32_16x16x32_bf16(Ah, xh[c], a, 0, 0, 0);
      a = __builtin_amdgcn_mfma_f32_16x16x32_bf16(Ah, xl[c], a, 0, 0, 0);
      a = __builtin_amdgcn_mfma_f32_16x16x32_bf16(Al, xh[c], a, 0, 0, 0);
    }
    acc[f] = a;
  }
  {
    float s1 = 0.f, s2 = 0.f;
#pragma unroll
    for (int f = 0; f < 8; ++f)
#pragma unroll
      for (int r = 0; r < 4; ++r) { float x = acc[f][r]; s1 += x; s2 = fmaf(x, x, s2); }
    s1 += __shfl_xor(s1, 16); s1 += __shfl_xor(s1, 32);
    s2 += __shfl_xor(s2, 16); s2 += __shfl_xor(s2, 32);
    float mean = s1 * (1.f / 128.f);
    float rstd = rsqrtf(fmaf(-mean, mean, s2 * (1.f / 128.f)) + EPS);
#pragma unroll
    for (int f = 0; f < 8; ++f) {
      float4 gv = *(const float4*)(g3 + 16 * f + 4 * q);
      float4 bv = *(const float4*)(b3 + 16 * f + 4 * q);
      float go[4] = {gv.x, gv.y, gv.z, gv.w};
      float bo[4] = {bv.x, bv.y, bv.z, bv.w};
      short4_t hi4, lo4;
#pragma unroll
      for (int r = 0; r < 4; ++r) {
        float t1 = fmaf((acc[f][r] - mean) * rstd, go[r], bo[r]);
        float v  = mish(t1);
        short hh = f2bf(v);
        hi4[r] = hh; lo4[r] = f2bf(v - bf2f(hh));
      }
      *(short4_t*)&xh18[r15 * 136 + 16 * f + 4 * q] = hi4;
      *(short4_t*)&xl18[r15 * 136 + 16 * f + 4 * q] = lo4;
    }
  }

  short8_t yh[4], yl[4];
#pragma unroll
  for (int c = 0; c < 4; ++c) {
    yh[c] = *(short8_t*)&xh18[r15 * 136 + 32 * c + 8 * q];
    yl[c] = *(short8_t*)&xl18[r15 * 136 + 32 * c + 8 * q];
  }
#pragma unroll
  for (int f = 0; f < 8; ++f) {
    fx4 a = zacc;
#pragma unroll
    for (int c = 0; c < 4; ++c) {
      int off = (16 * f + r15) * 128 + 32 * c + 8 * q;
      short8_t Ah = *(const short8_t*)&w3h[off];
      short8_t Al = *(const short8_t*)&w3l[off];
      a = __builtin_amdgcn_mfma_f32_16x16x32_bf16(Ah, yh[c], a, 0, 0, 0);
      a = __builtin_amdgcn_mfma_f32_16x16x32_bf16(Ah, yl[c], a, 0, 0, 0);
      a = __builtin_amdgcn_mfma_f32_16x16x32_bf16(Al, yh[c], a, 0, 0, 0);
    }
    acc[f] = a;
  }
  {
    float s1 = 0.f, s2 = 0.f;
#pragma unroll
    for (int f = 0; f < 8; ++f)
#pragma unroll
      for (int r = 0; r < 4; ++r) { float x = acc[f][r]; s1 += x; s2 = fmaf(x, x, s2); }
    s1 += __shfl_xor(s1, 16); s1 += __shfl_xor(s1, 32);
    s2 += __shfl_xor(s2, 16); s2 += __shfl_xor(s2, 32);
    float mean = s1 * (1.f / 128.f);
    float rstd = rsqrtf(fmaf(-mean, mean, s2 * (1.f / 128.f)) + EPS);

    int2 hw2 = *(const int2*)&bevcoors[cell * 2];   // (h, w)
    const int base = hw2.y * BEV_H + hw2.x;
#pragma unroll
    for (int f = 0; f < 8; ++f) {
      float4 gv = *(const float4*)(g3 + 16 * f + 4 * q);
      float4 bv = *(const float4*)(b3 + 16 * f + 4 * q);
      float go[4] = {gv.x, gv.y, gv.z, gv.w};
      float bo[4] = {bv.x, bv.y, bv.z, bv.w};
      float4 R = *(const float4*)(xr + 16 * f + 4 * q);   // residual x17
      float Ra[4] = {R.x, R.y, R.z, R.w};
#pragma unroll
      for (int r = 0; r < 4; ++r) {
        float t1 = fmaf((acc[f][r] - mean) * rstd, go[r], bo[r]);
        float val = mish(t1) + Ra[r];
        out[(size_t)(16 * f + 4 * q + r) * HW + base] = val;
      }
    }
  }
}

// ---------------------------------------------------------------------------
extern "C" void kernel_launch(void* const* d_in, const int* in_sizes, int n_in,
                              void* d_out, int out_size, void* d_ws, size_t ws_size,
                              hipStream_t stream) {
  const float* voxels   = (const float*)d_in[0];
  const float* vmask    = (const float*)d_in[1];
  const int*   bevsidx  = (const int*)d_in[2];
  const int*   bevcoors = (const int*)d_in[3];
  const float* bevmask  = (const float*)d_in[4];
  const float* vfe1_W = (const float*)d_in[5];
  const float* vfe1_g = (const float*)d_in[6];
  const float* vfe1_b = (const float*)d_in[7];
  const float* vfe2_W = (const float*)d_in[8];
  const float* vfe2_g = (const float*)d_in[9];
  const float* vfe2_b = (const float*)d_in[10];
  const float* vfe3_W = (const float*)d_in[11];
  const float* vfe3_g = (const float*)d_in[12];
  const float* vfe3_b = (const float*)d_in[13];
  const float* vfe4_W = (const float*)d_in[14];
  const float* vfe4_g = (const float*)d_in[15];
  const float* vfe4_b = (const float*)d_in[16];
  const float* bfe1_W  = (const float*)d_in[17];
  const float* bfe1_g  = (const float*)d_in[18];
  const float* bfe1_b  = (const float*)d_in[19];
  const float* bfe2a_W = (const float*)d_in[20];
  const float* bfe2a_g = (const float*)d_in[21];
  const float* bfe2a_b = (const float*)d_in[22];
  const float* bfe2b_W = (const float*)d_in[23];
  const float* bfe2b_g = (const float*)d_in[24];
  const float* bfe2b_b = (const float*)d_in[25];
  const float* bfe3_W  = (const float*)d_in[26];
  const float* bfe3_g  = (const float*)d_in[27];
  const float* bfe3_b  = (const float*)d_in[28];

  float* voxelwise = (float*)d_ws;                    // NV*CV floats
  float* x17buf    = voxelwise + NV * CV;             // NB*128 floats
  short* wbase     = (short*)(x17buf + (size_t)NB * 128);
  short* w1h  = wbase;                                // 65536
  short* w1l  = w1h + 65536;
  short* w2ah = w1l + 65536;                          // 16384
  short* w2al = w2ah + 16384;
  short* w2bh = w2al + 16384;                         // 8192
  short* w2bl = w2bh + 8192;
  short* w3h  = w2bl + 8192;                          // 16384
  short* w3l  = w3h + 16384;
  float* out = (float*)d_out;

  hipMemsetAsync(d_out, 0, (size_t)out_size * sizeof(float), stream);

  pack_weights_kernel<<<(106496 + 255) / 256, 256, 0, stream>>>(
      bfe1_W, bfe2a_W, bfe2b_W, bfe3_W,
      w1h, w1l, w2ah, w2al, w2bh, w2bl, w3h, w3l);

  vfe_mfma3_kernel<<<NV / 16, 256, 0, stream>>>(
      voxels, vmask,
      vfe1_W, vfe1_g, vfe1_b, vfe2_W, vfe2_g, vfe2_b,
      vfe3_W, vfe3_g, vfe3_b, vfe4_W, vfe4_g, vfe4_b,
      voxelwise);

  bfe12_mfma_kernel<<<NB / 8, 256, SMEM_SHORTS * sizeof(short), stream>>>(
      voxelwise, bevsidx, bevmask,
      w1h, w1l, bfe1_g, bfe1_b,
      w2ah, w2al, bfe2a_g, bfe2a_b,
      w2bh, w2bl, bfe2b_g, bfe2b_b,
      x17buf);

  bfe3_mfma_kernel<<<NB / 64, 256, 0, stream>>>(
      x17buf, bevcoors, w3h, w3l, bfe3_g, bfe3_b, out);
}

// Round 6
// 504.642 us; speedup vs baseline: 2.2468x; 1.0893x over previous
//
#include <hip/hip_runtime.h>
#include <math.h>

// Problem constants (from reference setup_inputs)
constexpr int NV  = 16000;   // voxels
constexpr int P   = 32;      // points per voxel
constexpr int CIN = 10;      // input channels
constexpr int CV  = 64;      // voxel feature channels
constexpr int NB  = 16000;   // BEV cells
constexpr int BEV_H = 496, BEV_W = 432;
constexpr int HW = BEV_H * BEV_W;  // 214272
constexpr float EPS = 1e-5f;

typedef __attribute__((ext_vector_type(8))) short short8_t;  // 8 bf16 (4 VGPR)
typedef __attribute__((ext_vector_type(4))) short short4_t;  // 4 bf16
typedef __attribute__((ext_vector_type(4))) float fx4;       // MFMA C/D frag

__device__ __forceinline__ float mish(float x) {
  float e = __expf(fminf(x, 15.f));
  float n = fmaf(e, e, 2.f * e);
  return x * __fdividef(n, n + 2.f);
}

__device__ __forceinline__ short f2bf(float f) {
  unsigned u = __builtin_bit_cast(unsigned, f);
  u += 0x7FFF + ((u >> 16) & 1);
  return (short)(u >> 16);
}
__device__ __forceinline__ float bf2f(short s) {
  unsigned u = ((unsigned)(unsigned short)s) << 16;
  return __builtin_bit_cast(float, u);
}
__device__ __forceinline__ short8_t pack8(const float* t) {
  short8_t s;
#pragma unroll
  for (int j = 0; j < 8; ++j) s[j] = f2bf(t[j]);
  return s;
}

// ---------------------------------------------------------------------------
// Prologue: split bfe weights into bf16 hi/lo. W2a/W2b o-padded to 16.
// Also splits bfe3_W (128x128). (bfe12 now uses only the hi arrays; bfe3
// still uses hi+lo.)
// ---------------------------------------------------------------------------
__global__ __launch_bounds__(256) void pack_weights_kernel(
    const float* __restrict__ W1, const float* __restrict__ W2a,
    const float* __restrict__ W2b, const float* __restrict__ W3,
    short* __restrict__ w1h, short* __restrict__ w1l,
    short* __restrict__ w2ah, short* __restrict__ w2al,
    short* __restrict__ w2bh, short* __restrict__ w2bl,
    short* __restrict__ w3h, short* __restrict__ w3l)
{
  int i = blockIdx.x * 256 + threadIdx.x;
  if (i < 65536) {
    float v = W1[i];
    short h = f2bf(v);
    w1h[i] = h; w1l[i] = f2bf(v - bf2f(h));
  } else if (i < 81920) {
    int j = i - 65536;
    int g = j >> 10, o = (j >> 6) & 15, c = j & 63;
    float v = (o < 8) ? W2a[(g * 8 + o) * 64 + c] : 0.f;
    short h = f2bf(v);
    w2ah[j] = h; w2al[j] = f2bf(v - bf2f(h));
  } else if (i < 90112) {
    int k = i - 81920;
    int g = k >> 9, o = (k >> 5) & 15, c = k & 31;
    float v = (o < 8) ? W2b[(g * 8 + o) * 32 + c] : 0.f;
    short h = f2bf(v);
    w2bh[k] = h; w2bl[k] = f2bf(v - bf2f(h));
  } else if (i < 106496) {
    int j = i - 90112;
    float v = W3[j];
    short h = f2bf(v);
    w3h[j] = h; w3l[j] = f2bf(v - bf2f(h));
  }
}

// ---------------------------------------------------------------------------
// VFE v3 (unchanged from round 5): weight A-frags in block-shared LDS;
// pure-register max epilogue.
// ---------------------------------------------------------------------------
__global__ __launch_bounds__(256, 3) void vfe_mfma3_kernel(
    const float* __restrict__ voxels, const float* __restrict__ vmask,
    const float* __restrict__ W1, const float* __restrict__ g1, const float* __restrict__ b1,
    const float* __restrict__ W2, const float* __restrict__ g2, const float* __restrict__ b2,
    const float* __restrict__ W3, const float* __restrict__ g3, const float* __restrict__ b3,
    const float* __restrict__ W4, const float* __restrict__ g4, const float* __restrict__ b4,
    float* __restrict__ voxelwise)
{
  __shared__ short wlds[28 * 512];
  __shared__ short actb[4][16 * 72];

  const int tid  = threadIdx.x;
  const int lane = tid & 63;
  const int w    = tid >> 6;
  const int p    = lane & 15;
  const int q    = lane >> 4;
  const int gw   = blockIdx.x * 4 + w;

  for (int s = w; s < 28; s += 4) {
    float t[8];
    if (s < 4) {
      const int f = s;
#pragma unroll
      for (int j = 0; j < 8; ++j) {
        int c = 8 * q + j;
        t[j] = (c < CIN) ? W1[(p + 16 * f) * CIN + c] : 0.f;
      }
    } else {
      const int l = (s - 4) >> 3, rem = (s - 4) & 7, ch = rem >> 2, f = rem & 3;
      const float* Wl = (l == 0) ? W2 : (l == 1) ? W3 : W4;
      const float* src = Wl + (p + 16 * f) * CV + 32 * ch + 8 * q;
#pragma unroll
      for (int j = 0; j < 8; ++j) t[j] = src[j];
    }
    *(short8_t*)&wlds[s * 512 + lane * 8] = pack8(t);
  }
  __syncthreads();

  short* mybuf = &actb[w][0];
  const fx4 zacc = {0.f, 0.f, 0.f, 0.f};
  const int srcLane = ((lane >> 2) & 3) * 16;

  for (int i = 0; i < 4; ++i) {
    const int v = gw * 4 + i;
    float chmax0 = 0.f, vmaxv = 0.f;

    for (int h = 0; h < 2; ++h) {
      const int ptbase = v * 32 + h * 16;
      const float m = vmask[ptbase + p];
      float x2r[16];
      float vmax[4][4];

      {
        const float* xrow = voxels + (size_t)(ptbase + p) * CIN;
        float t[8] = {0.f, 0.f, 0.f, 0.f, 0.f, 0.f, 0.f, 0.f};
        if (q == 0) {
          float2 a = *(const float2*)(xrow + 0);
          float2 b = *(const float2*)(xrow + 2);
          float2 c = *(const float2*)(xrow + 4);
          float2 d = *(const float2*)(xrow + 6);
          t[0] = a.x; t[1] = a.y; t[2] = b.x; t[3] = b.y;
          t[4] = c.x; t[5] = c.y; t[6] = d.x; t[7] = d.y;
        } else if (q == 1) {
          float2 a = *(const float2*)(xrow + 8);
          t[0] = a.x; t[1] = a.y;
        }
        short8_t bfrag = pack8(t);
        fx4 acc[4];
#pragma unroll
        for (int f = 0; f < 4; ++f) {
          short8_t af = *(short8_t*)&wlds[f * 512 + lane * 8];
          acc[f] = __builtin_amdgcn_mfma_f32_16x16x32_bf16(af, bfrag, zacc, 0, 0, 0);
        }
        float s1 = 0.f, s2 = 0.f;
#pragma unroll
        for (int f = 0; f < 4; ++f)
#pragma unroll
          for (int r = 0; r < 4; ++r) { float x = acc[f][r]; s1 += x; s2 = fmaf(x, x, s2); }
        s1 += __shfl_xor(s1, 16); s1 += __shfl_xor(s1, 32);
        s2 += __shfl_xor(s2, 16); s2 += __shfl_xor(s2, 32);
        float mean = s1 * (1.f / 64.f);
        float rstd = rsqrtf(fmaf(-mean, mean, s2 * (1.f / 64.f)) + EPS);
#pragma unroll
        for (int f = 0; f < 4; ++f) {
          float4 gv = *(const float4*)(g1 + 4 * q + 16 * f);
          float4 bv = *(const float4*)(b1 + 4 * q + 16 * f);
          float go[4] = {gv.x, gv.y, gv.z, gv.w};
          float bo[4] = {bv.x, bv.y, bv.z, bv.w};
          short4_t s4;
#pragma unroll
          for (int r = 0; r < 4; ++r) {
            float t1 = fmaf((acc[f][r] - mean) * rstd, go[r], bo[r]);
            s4[r] = f2bf(mish(t1));
          }
          *(short4_t*)&mybuf[p * 72 + 4 * q + 16 * f] = s4;
        }
      }

#pragma unroll 1
      for (int l = 0; l < 3; ++l) {
        short8_t bf0 = *(short8_t*)&mybuf[p * 72 + 8 * q];
        short8_t bf1 = *(short8_t*)&mybuf[p * 72 + 8 * q + 32];
        fx4 acc[4];
#pragma unroll
        for (int f = 0; f < 4; ++f) {
          short8_t a0 = *(short8_t*)&wlds[(4 + l * 8 + f) * 512 + lane * 8];
          short8_t a1 = *(short8_t*)&wlds[(4 + l * 8 + 4 + f) * 512 + lane * 8];
          fx4 a = __builtin_amdgcn_mfma_f32_16x16x32_bf16(a0, bf0, zacc, 0, 0, 0);
          acc[f] = __builtin_amdgcn_mfma_f32_16x16x32_bf16(a1, bf1, a, 0, 0, 0);
        }
        float s1 = 0.f, s2 = 0.f;
#pragma unroll
        for (int f = 0; f < 4; ++f)
#pragma unroll
          for (int r = 0; r < 4; ++r) { float x = acc[f][r]; s1 += x; s2 = fmaf(x, x, s2); }
        s1 += __shfl_xor(s1, 16); s1 += __shfl_xor(s1, 32);
        s2 += __shfl_xor(s2, 16); s2 += __shfl_xor(s2, 32);
        float mean = s1 * (1.f / 64.f);
        float rstd = rsqrtf(fmaf(-mean, mean, s2 * (1.f / 64.f)) + EPS);

        const float* gp = (l == 0) ? g2 : (l == 1) ? g3 : g4;
        const float* bp = (l == 0) ? b2 : (l == 1) ? b3 : b4;
#pragma unroll
        for (int f = 0; f < 4; ++f) {
          float4 gv = *(const float4*)(gp + 4 * q + 16 * f);
          float4 bv = *(const float4*)(bp + 4 * q + 16 * f);
          float go[4] = {gv.x, gv.y, gv.z, gv.w};
          float bo[4] = {bv.x, bv.y, bv.z, bv.w};
          if (l == 0) {
            short4_t s4;
#pragma unroll
            for (int r = 0; r < 4; ++r) {
              float t1 = fmaf((acc[f][r] - mean) * rstd, go[r], bo[r]);
              float a  = mish(t1) * m;
              x2r[f * 4 + r] = a;
              s4[r] = f2bf(a);
            }
            *(short4_t*)&mybuf[p * 72 + 4 * q + 16 * f] = s4;
          } else if (l == 1) {
            short4_t s4;
#pragma unroll
            for (int r = 0; r < 4; ++r) {
              float t1 = fmaf((acc[f][r] - mean) * rstd, go[r], bo[r]);
              s4[r] = f2bf(mish(t1));
            }
            *(short4_t*)&mybuf[p * 72 + 4 * q + 16 * f] = s4;
          } else {
#pragma unroll
            for (int r = 0; r < 4; ++r) {
              float t1 = fmaf((acc[f][r] - mean) * rstd, go[r], bo[r]);
              float v0 = fmaf(mish(t1), m, x2r[f * 4 + r]);
              v0 = fmaxf(v0, __shfl_xor(v0, 1));
              v0 = fmaxf(v0, __shfl_xor(v0, 2));
              v0 = fmaxf(v0, __shfl_xor(v0, 4));
              v0 = fmaxf(v0, __shfl_xor(v0, 8));
              vmax[f][r] = v0;
            }
          }
        }
      }

      float hm = 0.f;
#pragma unroll
      for (int f = 0; f < 4; ++f)
#pragma unroll
        for (int r = 0; r < 4; ++r) {
          float vsh = __shfl(vmax[f][r], srcLane);
          if (((lane >> 4) == f) && ((lane & 3) == r)) hm = vsh;
        }
      if (h == 0) chmax0 = hm; else vmaxv = fmaxf(chmax0, hm);
    }
    voxelwise[v * 64 + lane] = vmaxv;
  }
}

// ---------------------------------------------------------------------------
// Kernel 2 v2: bfe1 + bfe2a + bfe2b via MFMA, PLAIN bf16 (no hi/lo split).
// LDS ~33KB -> 4 blocks/CU. x-stage stride 72 shorts (2-way banks, free).
// Block = 8 cells x 4 waves; 4 stages; stage j: wave w runs group 4j+w.
// ---------------------------------------------------------------------------
constexpr int XS_CH   = 72;              // shorts per ch row (64 data + 8 pad)
constexpr int XS_CELL = 16 * 72 + 16;    // 1168 shorts/cell (16B aligned)
constexpr int ACT_OFF = 8 * XS_CELL;                 // 9344
constexpr int ACT_WS  = 16 * 72;                     // 1152 per wave
constexpr int H2_OFF  = ACT_OFF + 4 * ACT_WS;        // 13952
constexpr int H2_WS   = 16 * 40;                     // 640 per wave
constexpr int SMEM_SHORTS = H2_OFF + 4 * H2_WS;      // 16512 shorts = 33024 B

__global__ __launch_bounds__(256, 4) void bfe12_mfma2_kernel(
    const float* __restrict__ voxelwise, const int* __restrict__ bevsidx,
    const float* __restrict__ bevmask,
    const short* __restrict__ w1h,
    const float* __restrict__ g1, const float* __restrict__ b1,
    const short* __restrict__ w2ah,
    const float* __restrict__ g2a, const float* __restrict__ b2a,
    const short* __restrict__ w2bh,
    const float* __restrict__ g2b, const float* __restrict__ b2b,
    float* __restrict__ x17buf)
{
  extern __shared__ short sm[];

  const int tid  = threadIdx.x;
  const int lane = tid & 63;
  const int w    = tid >> 6;
  const int r15  = lane & 15;
  const int q    = lane >> 4;
  const int cellbase = blockIdx.x * 8;

  const int chq   = lane & 3;
  const int v_loc = (lane >> 2) & 3;
  const int vblk  = lane >> 4;
  const int bit0  = v_loc & 1, bit1 = v_loc >> 1;

  int idxr[2][4];
#pragma unroll
  for (int cc = 0; cc < 2; ++cc)
#pragma unroll
    for (int vb = 0; vb < 4; ++vb) {
      int v = 16 * vb + 4 * vblk + v_loc;
      idxr[cc][vb] = bevsidx[(cellbase + 2 * w + cc) * 64 + v];
    }

  // zero h2 pad rows (8..15) — wave-private, once
  {
    short* zh = &sm[H2_OFF + w * H2_WS];
    for (int i = lane; i < 320; i += 64) zh[320 + i] = 0;
  }

  const fx4 zacc = {0.f, 0.f, 0.f, 0.f};
  short* acth = &sm[ACT_OFF + w * ACT_WS];
  short* h2h  = &sm[H2_OFF + w * H2_WS];

#pragma unroll 1
  for (int j = 0; j < 4; ++j) {
    const int g = 4 * j + w;

    __syncthreads();   // prior stage's x reads complete

    // ---- gather 16-ch slice (ch = 16j..16j+15) of my 2 cells into LDS ----
#pragma unroll
    for (int cc = 0; cc < 2; ++cc) {
#pragma unroll
      for (int vb = 0; vb < 4; ++vb) {
        const float* src = voxelwise + (size_t)idxr[cc][vb] * 64 + 16 * j + 4 * chq;
        float4 f4 = *(const float4*)src;
        float a0 = f4.x, a1 = f4.y, a2 = f4.z, a3 = f4.w;
        float gv0 = bit0 ? a0 : a1, gv1 = bit0 ? a2 : a3;
        float r0 = __shfl_xor(gv0, 4), r1 = __shfl_xor(gv1, 4);
        float c0 = bit0 ? r0 : a0, c1 = bit0 ? a1 : r0;
        float c2 = bit0 ? r1 : a2, c3 = bit0 ? a3 : r1;
        float h0 = bit1 ? c0 : c2, h1 = bit1 ? c1 : c3;
        float s0 = __shfl_xor(h0, 8), s1 = __shfl_xor(h1, 8);
        float d0 = bit1 ? s0 : c0, d1 = bit1 ? s1 : c1;
        float d2 = bit1 ? c2 : s0, d3 = bit1 ? c3 : s1;
        float dv[4] = {d0, d1, d2, d3};
        short4_t hi4;
#pragma unroll
        for (int r = 0; r < 4; ++r) hi4[r] = f2bf(dv[r]);
        int addr = (2 * w + cc) * XS_CELL + (4 * chq + v_loc) * XS_CH + 16 * vb + 4 * vblk;
        *(short4_t*)&sm[addr] = hi4;
      }
    }

    __syncthreads();   // x slice ready for all waves

    // ---- A-frags for group g (global hi only, L2-hot) ----
    short8_t W1f[2][4];
#pragma unroll
    for (int c = 0; c < 2; ++c)
#pragma unroll
      for (int f = 0; f < 4; ++f) {
        int off = (g * 64 + r15 + 16 * f) * 64 + 32 * c + 8 * q;
        W1f[c][f] = *(const short8_t*)&w1h[off];
      }
    short8_t W2af[2];
#pragma unroll
    for (int c = 0; c < 2; ++c) {
      int off = (g * 16 + r15) * 64 + 32 * c + 8 * q;
      W2af[c] = *(const short8_t*)&w2ah[off];
    }
    short8_t W2bf;
    {
      int off = (g * 16 + r15) * 32 + 8 * q;
      W2bf = *(const short8_t*)&w2bh[off];
    }

    // ---- 2 tiles of 4 cells ----
#pragma unroll 1
    for (int t = 0; t < 2; ++t) {
      const int cl = r15 >> 2, p = r15 & 3;
      const int cell_loc = 4 * t + cl;
      const float bm = bevmask[cellbase + cell_loc];

      int xaddr = cell_loc * XS_CELL + (4 * w + p) * XS_CH;
      short8_t x0 = *(short8_t*)&sm[xaddr + 8 * q];
      short8_t x1 = *(short8_t*)&sm[xaddr + 32 + 8 * q];

      fx4 acc[4];
#pragma unroll
      for (int f = 0; f < 4; ++f) {
        fx4 a = __builtin_amdgcn_mfma_f32_16x16x32_bf16(W1f[0][f], x0, zacc, 0, 0, 0);
        acc[f] = __builtin_amdgcn_mfma_f32_16x16x32_bf16(W1f[1][f], x1, a, 0, 0, 0);
      }

      float s1 = 0.f, s2 = 0.f;
#pragma unroll
      for (int f = 0; f < 4; ++f)
#pragma unroll
        for (int r = 0; r < 4; ++r) { float x = acc[f][r]; s1 += x; s2 = fmaf(x, x, s2); }
      s1 += __shfl_xor(s1, 16); s1 += __shfl_xor(s1, 32);
      s2 += __shfl_xor(s2, 16); s2 += __shfl_xor(s2, 32);
      float mean = s1 * (1.f / 64.f);
      float rstd = rsqrtf(fmaf(-mean, mean, s2 * (1.f / 64.f)) + EPS);

#pragma unroll
      for (int f = 0; f < 4; ++f) {
        float4 gv = *(const float4*)(g1 + g * 64 + 16 * f + 4 * q);
        float4 bv = *(const float4*)(b1 + g * 64 + 16 * f + 4 * q);
        float go[4] = {gv.x, gv.y, gv.z, gv.w};
        float bo[4] = {bv.x, bv.y, bv.z, bv.w};
        short4_t hi4;
#pragma unroll
        for (int r = 0; r < 4; ++r) {
          float t1 = fmaf((acc[f][r] - mean) * rstd, go[r], bo[r]);
          hi4[r] = f2bf(mish(t1) * bm);
        }
        *(short4_t*)&acth[r15 * 72 + 16 * f + 4 * q] = hi4;
      }

      // bfe2a (same-wave LDS roundtrip)
      short8_t a0 = *(short8_t*)&acth[r15 * 72 + 8 * q];
      short8_t a1 = *(short8_t*)&acth[r15 * 72 + 32 + 8 * q];
      fx4 a2 = __builtin_amdgcn_mfma_f32_16x16x32_bf16(W2af[0], a0, zacc, 0, 0, 0);
      a2 = __builtin_amdgcn_mfma_f32_16x16x32_bf16(W2af[1], a1, a2, 0, 0, 0);

      float sa = a2[0] + a2[1] + a2[2] + a2[3];
      float sb = fmaf(a2[0], a2[0], fmaf(a2[1], a2[1], fmaf(a2[2], a2[2], a2[3] * a2[3])));
      sa += __shfl_xor(sa, 16); sb += __shfl_xor(sb, 16);
      if (q < 2) {
        float mean2 = sa * 0.125f;
        float rstd2 = rsqrtf(fmaf(-mean2, mean2, sb * 0.125f) + EPS);
        float4 gv = *(const float4*)(g2a + g * 8 + 4 * q);
        float4 bv = *(const float4*)(b2a + g * 8 + 4 * q);
        float go[4] = {gv.x, gv.y, gv.z, gv.w};
        float bo[4] = {bv.x, bv.y, bv.z, bv.w};
        short4_t hi4;
#pragma unroll
        for (int r = 0; r < 4; ++r) {
          float t1 = fmaf((a2[r] - mean2) * rstd2, go[r], bo[r]);
          hi4[r] = f2bf(mish(t1));
        }
        *(short4_t*)&h2h[cell_loc * 40 + p * 8 + 4 * q] = hi4;
      }
    }

    // ---- bfe2b: rows = 8 cells (+8 zero pad), K=32 ----
    {
      short8_t bh = *(short8_t*)&h2h[r15 * 40 + 8 * q];
      fx4 a3 = __builtin_amdgcn_mfma_f32_16x16x32_bf16(W2bf, bh, zacc, 0, 0, 0);

      float sa = a3[0] + a3[1] + a3[2] + a3[3];
      float sb = fmaf(a3[0], a3[0], fmaf(a3[1], a3[1], fmaf(a3[2], a3[2], a3[3] * a3[3])));
      sa += __shfl_xor(sa, 16); sb += __shfl_xor(sb, 16);
      if (q < 2 && r15 < 8) {
        float mean3 = sa * 0.125f;
        float rstd3 = rsqrtf(fmaf(-mean3, mean3, sb * 0.125f) + EPS);
        float4 gv = *(const float4*)(g2b + g * 8 + 4 * q);
        float4 bv = *(const float4*)(b2b + g * 8 + 4 * q);
        float go[4] = {gv.x, gv.y, gv.z, gv.w};
        float bo[4] = {bv.x, bv.y, bv.z, bv.w};
        float4 outv;
        float* op = &outv.x;
#pragma unroll
        for (int r = 0; r < 4; ++r) {
          float t1 = fmaf((a3[r] - mean3) * rstd3, go[r], bo[r]);
          op[r] = mish(t1);
        }
        *(float4*)&x17buf[(size_t)(cellbase + r15) * 128 + g * 8 + 4 * q] = outv;
      }
    }
  }
}

// ---------------------------------------------------------------------------
// Kernel 3: bfe3 twice + residual + scatter via MFMA, split-precision
// (unchanged from round 5).
// ---------------------------------------------------------------------------
__global__ __launch_bounds__(256, 2) void bfe3_mfma_kernel(
    const float* __restrict__ x17buf, const int* __restrict__ bevcoors,
    const short* __restrict__ w3h, const short* __restrict__ w3l,
    const float* __restrict__ g3, const float* __restrict__ b3,
    float* __restrict__ out)
{
  __shared__ short x18h[4][16 * 136];
  __shared__ short x18l[4][16 * 136];

  const int tid  = threadIdx.x;
  const int lane = tid & 63;
  const int w    = tid >> 6;
  const int r15  = lane & 15;
  const int q    = lane >> 4;
  const int cell = blockIdx.x * 64 + w * 16 + r15;
  const float* xr = x17buf + (size_t)cell * 128;
  short* xh18 = &x18h[w][0];
  short* xl18 = &x18l[w][0];
  const fx4 zacc = {0.f, 0.f, 0.f, 0.f};

  short8_t xh[4], xl[4];
#pragma unroll
  for (int c = 0; c < 4; ++c) {
    const float* s = xr + 32 * c + 8 * q;
    float4 A = *(const float4*)s;
    float4 B = *(const float4*)(s + 4);
    float t[8] = {A.x, A.y, A.z, A.w, B.x, B.y, B.z, B.w};
    short8_t hi, lo;
#pragma unroll
    for (int jj = 0; jj < 8; ++jj) {
      short hh = f2bf(t[jj]);
      hi[jj] = hh; lo[jj] = f2bf(t[jj] - bf2f(hh));
    }
    xh[c] = hi; xl[c] = lo;
  }

  fx4 acc[8];
#pragma unroll
  for (int f = 0; f < 8; ++f) {
    fx4 a = zacc;
#pragma unroll
    for (int c = 0; c < 4; ++c) {
      int off = (16 * f + r15) * 128 + 32 * c + 8 * q;
      short8_t Ah = *(const short8_t*)&w3h[off];
      short8_t Al = *(const short8_t*)&w3l[off];
      a = __builtin_amdgcn_mfma_f32_16x16x32_bf16(Ah, xh[c], a, 0, 0, 0);
      a = __builtin_amdgcn_mfma_f32_16x16x32_bf16(Ah, xl[c], a, 0, 0, 0);
      a = __builtin_amdgcn_mfma_f32_16x16x32_bf16(Al, xh[c], a, 0, 0, 0);
    }
    acc[f] = a;
  }
  {
    float s1 = 0.f, s2 = 0.f;
#pragma unroll
    for (int f = 0; f < 8; ++f)
#pragma unroll
      for (int r = 0; r < 4; ++r) { float x = acc[f][r]; s1 += x; s2 = fmaf(x, x, s2); }
    s1 += __shfl_xor(s1, 16); s1 += __shfl_xor(s1, 32);
    s2 += __shfl_xor(s2, 16); s2 += __shfl_xor(s2, 32);
    float mean = s1 * (1.f / 128.f);
    float rstd = rsqrtf(fmaf(-mean, mean, s2 * (1.f / 128.f)) + EPS);
#pragma unroll
    for (int f = 0; f < 8; ++f) {
      float4 gv = *(const float4*)(g3 + 16 * f + 4 * q);
      float4 bv = *(const float4*)(b3 + 16 * f + 4 * q);
      float go[4] = {gv.x, gv.y, gv.z, gv.w};
      float bo[4] = {bv.x, bv.y, bv.z, bv.w};
      short4_t hi4, lo4;
#pragma unroll
      for (int r = 0; r < 4; ++r) {
        float t1 = fmaf((acc[f][r] - mean) * rstd, go[r], bo[r]);
        float v  = mish(t1);
        short hh = f2bf(v);
        hi4[r] = hh; lo4[r] = f2bf(v - bf2f(hh));
      }
      *(short4_t*)&xh18[r15 * 136 + 16 * f + 4 * q] = hi4;
      *(short4_t*)&xl18[r15 * 136 + 16 * f + 4 * q] = lo4;
    }
  }

  short8_t yh[4], yl[4];
#pragma unroll
  for (int c = 0; c < 4; ++c) {
    yh[c] = *(short8_t*)&xh18[r15 * 136 + 32 * c + 8 * q];
    yl[c] = *(short8_t*)&xl18[r15 * 136 + 32 * c + 8 * q];
  }
#pragma unroll
  for (int f = 0; f < 8; ++f) {
    fx4 a = zacc;
#pragma unroll
    for (int c = 0; c < 4; ++c) {
      int off = (16 * f + r15) * 128 + 32 * c + 8 * q;
      short8_t Ah = *(const short8_t*)&w3h[off];
      short8_t Al = *(const short8_t*)&w3l[off];
      a = __builtin_amdgcn_mfma_f32_16x16x32_bf16(Ah, yh[c], a, 0, 0, 0);
      a = __builtin_amdgcn_mfma_f32_16x16x32_bf16(Ah, yl[c], a, 0, 0, 0);
      a = __builtin_amdgcn_mfma_f32_16x16x32_bf16(Al, yh[c], a, 0, 0, 0);
    }
    acc[f] = a;
  }
  {
    float s1 = 0.f, s2 = 0.f;
#pragma unroll
    for (int f = 0; f < 8; ++f)
#pragma unroll
      for (int r = 0; r < 4; ++r) { float x = acc[f][r]; s1 += x; s2 = fmaf(x, x, s2); }
    s1 += __shfl_xor(s1, 16); s1 += __shfl_xor(s1, 32);
    s2 += __shfl_xor(s2, 16); s2 += __shfl_xor(s2, 32);
    float mean = s1 * (1.f / 128.f);
    float rstd = rsqrtf(fmaf(-mean, mean, s2 * (1.f / 128.f)) + EPS);

    int2 hw2 = *(const int2*)&bevcoors[cell * 2];   // (h, w)
    const int base = hw2.y * BEV_H + hw2.x;
#pragma unroll
    for (int f = 0; f < 8; ++f) {
      float4 gv = *(const float4*)(g3 + 16 * f + 4 * q);
      float4 bv = *(const float4*)(b3 + 16 * f + 4 * q);
      float go[4] = {gv.x, gv.y, gv.z, gv.w};
      float bo[4] = {bv.x, bv.y, bv.z, bv.w};
      float4 R = *(const float4*)(xr + 16 * f + 4 * q);
      float Ra[4] = {R.x, R.y, R.z, R.w};
#pragma unroll
      for (int r = 0; r < 4; ++r) {
        float t1 = fmaf((acc[f][r] - mean) * rstd, go[r], bo[r]);
        float val = mish(t1) + Ra[r];
        out[(size_t)(16 * f + 4 * q + r) * HW + base] = val;
      }
    }
  }
}

// ---------------------------------------------------------------------------
extern "C" void kernel_launch(void* const* d_in, const int* in_sizes, int n_in,
                              void* d_out, int out_size, void* d_ws, size_t ws_size,
                              hipStream_t stream) {
  const float* voxels   = (const float*)d_in[0];
  const float* vmask    = (const float*)d_in[1];
  const int*   bevsidx  = (const int*)d_in[2];
  const int*   bevcoors = (const int*)d_in[3];
  const float* bevmask  = (const float*)d_in[4];
  const float* vfe1_W = (const float*)d_in[5];
  const float* vfe1_g = (const float*)d_in[6];
  const float* vfe1_b = (const float*)d_in[7];
  const float* vfe2_W = (const float*)d_in[8];
  const float* vfe2_g = (const float*)d_in[9];
  const float* vfe2_b = (const float*)d_in[10];
  const float* vfe3_W = (const float*)d_in[11];
  const float* vfe3_g = (const float*)d_in[12];
  const float* vfe3_b = (const float*)d_in[13];
  const float* vfe4_W = (const float*)d_in[14];
  const float* vfe4_g = (const float*)d_in[15];
  const float* vfe4_b = (const float*)d_in[16];
  const float* bfe1_W  = (const float*)d_in[17];
  const float* bfe1_g  = (const float*)d_in[18];
  const float* bfe1_b  = (const float*)d_in[19];
  const float* bfe2a_W = (const float*)d_in[20];
  const float* bfe2a_g = (const float*)d_in[21];
  const float* bfe2a_b = (const float*)d_in[22];
  const float* bfe2b_W = (const float*)d_in[23];
  const float* bfe2b_g = (const float*)d_in[24];
  const float* bfe2b_b = (const float*)d_in[25];
  const float* bfe3_W  = (const float*)d_in[26];
  const float* bfe3_g  = (const float*)d_in[27];
  const float* bfe3_b  = (const float*)d_in[28];

  float* voxelwise = (float*)d_ws;                    // NV*CV floats
  float* x17buf    = voxelwise + NV * CV;             // NB*128 floats
  short* wbase     = (short*)(x17buf + (size_t)NB * 128);
  short* w1h  = wbase;                                // 65536
  short* w1l  = w1h + 65536;
  short* w2ah = w1l + 65536;                          // 16384
  short* w2al = w2ah + 16384;
  short* w2bh = w2al + 16384;                         // 8192
  short* w2bl = w2bh + 8192;
  short* w3h  = w2bl + 8192;                          // 16384
  short* w3l  = w3h + 16384;
  float* out = (float*)d_out;

  hipMemsetAsync(d_out, 0, (size_t)out_size * sizeof(float), stream);

  pack_weights_kernel<<<(106496 + 255) / 256, 256, 0, stream>>>(
      bfe1_W, bfe2a_W, bfe2b_W, bfe3_W,
      w1h, w1l, w2ah, w2al, w2bh, w2bl, w3h, w3l);

  vfe_mfma3_kernel<<<NV / 16, 256, 0, stream>>>(
      voxels, vmask,
      vfe1_W, vfe1_g, vfe1_b, vfe2_W, vfe2_g, vfe2_b,
      vfe3_W, vfe3_g, vfe3_b, vfe4_W, vfe4_g, vfe4_b,
      voxelwise);

  bfe12_mfma2_kernel<<<NB / 8, 256, SMEM_SHORTS * sizeof(short), stream>>>(
      voxelwise, bevsidx, bevmask,
      w1h, bfe1_g, bfe1_b,
      w2ah, bfe2a_g, bfe2a_b,
      w2bh, bfe2b_g, bfe2b_b,
      x17buf);

  bfe3_mfma_kernel<<<NB / 64, 256, 0, stream>>>(
      x17buf, bevcoors, w3h, w3l, bfe3_g, bfe3_b, out);
}

// Round 7
// 429.847 us; speedup vs baseline: 2.6377x; 1.1740x over previous
//
#include <hip/hip_runtime.h>
#include <math.h>

// Problem constants (from reference setup_inputs)
constexpr int NV  = 16000;   // voxels
constexpr int P   = 32;      // points per voxel
constexpr int CIN = 10;      // input channels
constexpr int CV  = 64;      // voxel feature channels
constexpr int NB  = 16000;   // BEV cells
constexpr int BEV_H = 496, BEV_W = 432;
constexpr int HW = BEV_H * BEV_W;  // 214272
constexpr float EPS = 1e-5f;

typedef __attribute__((ext_vector_type(8))) short short8_t;  // 8 bf16 (4 VGPR)
typedef __attribute__((ext_vector_type(4))) short short4_t;  // 4 bf16
typedef __attribute__((ext_vector_type(4))) float fx4;       // MFMA C/D frag
typedef __attribute__((ext_vector_type(2))) float f32x2;     // packed f32 pair

// 8-op mish: tanh(softplus(x)) = 1 - 2/((1+e^x)^2+1)  ->  mish = x - 2x/d
__device__ __forceinline__ float mish(float x) {
  float e = __expf(fminf(x, 15.f));
  float u = 1.f + e;
  float d = fmaf(u, u, 1.f);
  float r = __builtin_amdgcn_rcpf(d);
  return fmaf(-2.f * x, r, x);
}

// RNE f32->bf16 (cold paths: weight packing)
__device__ __forceinline__ short f2bf(float f) {
  unsigned u = __builtin_bit_cast(unsigned, f);
  u += 0x7FFF + ((u >> 16) & 1);
  return (short)(u >> 16);
}
__device__ __forceinline__ float bf2f(short s) {
  unsigned u = ((unsigned)(unsigned short)s) << 16;
  return __builtin_bit_cast(float, u);
}
__device__ __forceinline__ short8_t pack8(const float* t) {
  short8_t s;
#pragma unroll
  for (int j = 0; j < 8; ++j) s[j] = f2bf(t[j]);
  return s;
}

// hot-path pack: round-half-up + v_perm pair  (low16 = bf16(a), high16 = bf16(b))
__device__ __forceinline__ unsigned bfpair(float a, float b) {
  unsigned au = __builtin_bit_cast(unsigned, a) + 0x8000u;
  unsigned bu = __builtin_bit_cast(unsigned, b) + 0x8000u;
  return __builtin_amdgcn_perm(bu, au, 0x07060302u);
}
// Dekker-style split pair: returns hi-pack, writes exact lo residuals
__device__ __forceinline__ unsigned hipack(float a, float b, float& la, float& lb) {
  unsigned ua = (__builtin_bit_cast(unsigned, a) + 0x8000u) & 0xFFFF0000u;
  unsigned ub = (__builtin_bit_cast(unsigned, b) + 0x8000u) & 0xFFFF0000u;
  la = a - __builtin_bit_cast(float, ua);
  lb = b - __builtin_bit_cast(float, ub);
  return __builtin_amdgcn_perm(ub, ua, 0x07060302u);
}

// ---------------------------------------------------------------------------
// Prologue: split bfe weights into bf16 hi/lo (RNE, cold). W2a/W2b o-padded.
// ---------------------------------------------------------------------------
__global__ __launch_bounds__(256) void pack_weights_kernel(
    const float* __restrict__ W1, const float* __restrict__ W2a,
    const float* __restrict__ W2b, const float* __restrict__ W3,
    short* __restrict__ w1h, short* __restrict__ w1l,
    short* __restrict__ w2ah, short* __restrict__ w2al,
    short* __restrict__ w2bh, short* __restrict__ w2bl,
    short* __restrict__ w3h, short* __restrict__ w3l)
{
  int i = blockIdx.x * 256 + threadIdx.x;
  if (i < 65536) {
    float v = W1[i];
    short h = f2bf(v);
    w1h[i] = h; w1l[i] = f2bf(v - bf2f(h));
  } else if (i < 81920) {
    int j = i - 65536;
    int g = j >> 10, o = (j >> 6) & 15, c = j & 63;
    float v = (o < 8) ? W2a[(g * 8 + o) * 64 + c] : 0.f;
    short h = f2bf(v);
    w2ah[j] = h; w2al[j] = f2bf(v - bf2f(h));
  } else if (i < 90112) {
    int k = i - 81920;
    int g = k >> 9, o = (k >> 5) & 15, c = k & 31;
    float v = (o < 8) ? W2b[(g * 8 + o) * 32 + c] : 0.f;
    short h = f2bf(v);
    w2bh[k] = h; w2bl[k] = f2bf(v - bf2f(h));
  } else if (i < 106496) {
    int j = i - 90112;
    float v = W3[j];
    short h = f2bf(v);
    w3h[j] = h; w3l[j] = f2bf(v - bf2f(h));
  }
}

// ---------------------------------------------------------------------------
// VFE v4: LDS weights + LDS g/b; cheap packs; pk-f32 LN sums; 2-fma LN apply;
// reduce-scatter max epilogue (15 shfl + 1 transpose shfl).
// Grid: 1000 blocks x 4 waves, 4 voxels per wave.
// ---------------------------------------------------------------------------
__global__ __launch_bounds__(256, 4) void vfe_mfma4_kernel(
    const float* __restrict__ voxels, const float* __restrict__ vmask,
    const float* __restrict__ W1, const float* __restrict__ g1, const float* __restrict__ b1,
    const float* __restrict__ W2, const float* __restrict__ g2, const float* __restrict__ b2,
    const float* __restrict__ W3, const float* __restrict__ g3, const float* __restrict__ b3,
    const float* __restrict__ W4, const float* __restrict__ g4, const float* __restrict__ b4,
    float* __restrict__ voxelwise)
{
  __shared__ short wlds[28 * 512];     // 28,672 B: shared A-frags
  __shared__ short actb[4][16 * 72];   // 9,216 B: wave-private act slabs
  __shared__ float gblds[512];         // 2,048 B: g/b per layer

  const int tid  = threadIdx.x;
  const int lane = tid & 63;
  const int w    = tid >> 6;
  const int p    = lane & 15;
  const int q    = lane >> 4;
  const int gw   = blockIdx.x * 4 + w;

  // ---- stage g/b into LDS: gblds[(2*layer+gb)*64 + ch] ----
  for (int k = tid; k < 512; k += 256) {
    int region = k >> 6, off = k & 63;
    const float* src =
        region == 0 ? g1 : region == 1 ? b1 :
        region == 2 ? g2 : region == 3 ? b2 :
        region == 4 ? g3 : region == 5 ? b3 :
        region == 6 ? g4 : b4;
    gblds[k] = src[off];
  }
  // ---- stage weight A-frags into LDS (cooperative) ----
  for (int s = w; s < 28; s += 4) {
    float t[8];
    if (s < 4) {
      const int f = s;
#pragma unroll
      for (int j = 0; j < 8; ++j) {
        int c = 8 * q + j;
        t[j] = (c < CIN) ? W1[(p + 16 * f) * CIN + c] : 0.f;
      }
    } else {
      const int l = (s - 4) >> 3, rem = (s - 4) & 7, ch = rem >> 2, f = rem & 3;
      const float* Wl = (l == 0) ? W2 : (l == 1) ? W3 : W4;
      const float* src = Wl + (p + 16 * f) * CV + 32 * ch + 8 * q;
#pragma unroll
      for (int j = 0; j < 8; ++j) t[j] = src[j];
    }
    *(short8_t*)&wlds[s * 512 + lane * 8] = pack8(t);
  }
  __syncthreads();

  short* mybuf = &actb[w][0];
  const fx4 zacc = {0.f, 0.f, 0.f, 0.f};
  // transpose source lane: channel L lives in group (L>>2)&3 at lane 4*f*+r*
  const int srcLane = ((lane >> 2) & 3) * 16 + (((lane >> 4) & 3) << 2) + (lane & 3);

  for (int i = 0; i < 4; ++i) {
    const int v = gw * 4 + i;
    float chmax0 = 0.f, vmaxv = 0.f;

    for (int h = 0; h < 2; ++h) {
      const int ptbase = v * 32 + h * 16;
      const float m = vmask[ptbase + p];
      float x2r[16];
      float cur[16];   // layer-4 per-point values, index j = 4f + r

      // ---- layer 1 ----
      {
        const float* xrow = voxels + (size_t)(ptbase + p) * CIN;
        float t[8] = {0.f, 0.f, 0.f, 0.f, 0.f, 0.f, 0.f, 0.f};
        if (q == 0) {
          float2 a = *(const float2*)(xrow + 0);
          float2 b = *(const float2*)(xrow + 2);
          float2 c = *(const float2*)(xrow + 4);
          float2 d = *(const float2*)(xrow + 6);
          t[0] = a.x; t[1] = a.y; t[2] = b.x; t[3] = b.y;
          t[4] = c.x; t[5] = c.y; t[6] = d.x; t[7] = d.y;
        } else if (q == 1) {
          float2 a = *(const float2*)(xrow + 8);
          t[0] = a.x; t[1] = a.y;
        }
        uint4 bu = make_uint4(bfpair(t[0], t[1]), bfpair(t[2], t[3]),
                              bfpair(t[4], t[5]), bfpair(t[6], t[7]));
        short8_t bfrag = __builtin_bit_cast(short8_t, bu);
        fx4 acc[4];
#pragma unroll
        for (int f = 0; f < 4; ++f) {
          short8_t af = *(short8_t*)&wlds[f * 512 + lane * 8];
          acc[f] = __builtin_amdgcn_mfma_f32_16x16x32_bf16(af, bfrag, zacc, 0, 0, 0);
        }
        f32x2 s1v = {0.f, 0.f}, s2v = {0.f, 0.f};
#pragma unroll
        for (int f = 0; f < 4; ++f) {
          f32x2 a01 = __builtin_shufflevector(acc[f], acc[f], 0, 1);
          f32x2 a23 = __builtin_shufflevector(acc[f], acc[f], 2, 3);
          s1v = s1v + a01 + a23;
          s2v = __builtin_elementwise_fma(a01, a01, s2v);
          s2v = __builtin_elementwise_fma(a23, a23, s2v);
        }
        float s1 = s1v[0] + s1v[1], s2 = s2v[0] + s2v[1];
        s1 += __shfl_xor(s1, 16); s1 += __shfl_xor(s1, 32);
        s2 += __shfl_xor(s2, 16); s2 += __shfl_xor(s2, 32);
        float mean = s1 * (1.f / 64.f);
        float rstd = rsqrtf(fmaf(-mean, mean, s2 * (1.f / 64.f)) + EPS);
        float ms = -mean * rstd;
#pragma unroll
        for (int f = 0; f < 4; ++f) {
          float4 gv = *(const float4*)&gblds[0 * 128 + 16 * f + 4 * q];
          float4 bv = *(const float4*)&gblds[0 * 128 + 64 + 16 * f + 4 * q];
          float go[4] = {gv.x, gv.y, gv.z, gv.w};
          float bo[4] = {bv.x, bv.y, bv.z, bv.w};
          float o[4];
#pragma unroll
          for (int r = 0; r < 4; ++r)
            o[r] = mish(fmaf(fmaf(acc[f][r], rstd, ms), go[r], bo[r]));
          *(uint2*)&mybuf[p * 72 + 4 * q + 16 * f] =
              make_uint2(bfpair(o[0], o[1]), bfpair(o[2], o[3]));
        }
      }

      // ---- layers 2..4 ----
#pragma unroll 1
      for (int l = 0; l < 3; ++l) {
        short8_t bf0 = *(short8_t*)&mybuf[p * 72 + 8 * q];
        short8_t bf1 = *(short8_t*)&mybuf[p * 72 + 8 * q + 32];
        fx4 acc[4];
#pragma unroll
        for (int f = 0; f < 4; ++f) {
          short8_t a0 = *(short8_t*)&wlds[(4 + l * 8 + f) * 512 + lane * 8];
          short8_t a1 = *(short8_t*)&wlds[(4 + l * 8 + 4 + f) * 512 + lane * 8];
          fx4 a = __builtin_amdgcn_mfma_f32_16x16x32_bf16(a0, bf0, zacc, 0, 0, 0);
          acc[f] = __builtin_amdgcn_mfma_f32_16x16x32_bf16(a1, bf1, a, 0, 0, 0);
        }
        f32x2 s1v = {0.f, 0.f}, s2v = {0.f, 0.f};
#pragma unroll
        for (int f = 0; f < 4; ++f) {
          f32x2 a01 = __builtin_shufflevector(acc[f], acc[f], 0, 1);
          f32x2 a23 = __builtin_shufflevector(acc[f], acc[f], 2, 3);
          s1v = s1v + a01 + a23;
          s2v = __builtin_elementwise_fma(a01, a01, s2v);
          s2v = __builtin_elementwise_fma(a23, a23, s2v);
        }
        float s1 = s1v[0] + s1v[1], s2 = s2v[0] + s2v[1];
        s1 += __shfl_xor(s1, 16); s1 += __shfl_xor(s1, 32);
        s2 += __shfl_xor(s2, 16); s2 += __shfl_xor(s2, 32);
        float mean = s1 * (1.f / 64.f);
        float rstd = rsqrtf(fmaf(-mean, mean, s2 * (1.f / 64.f)) + EPS);
        float ms = -mean * rstd;
        const int gbbase = (l + 1) * 128;
#pragma unroll
        for (int f = 0; f < 4; ++f) {
          float4 gv = *(const float4*)&gblds[gbbase + 16 * f + 4 * q];
          float4 bv = *(const float4*)&gblds[gbbase + 64 + 16 * f + 4 * q];
          float go[4] = {gv.x, gv.y, gv.z, gv.w};
          float bo[4] = {bv.x, bv.y, bv.z, bv.w};
          if (l == 0) {            // layer 2: *mask, keep residual
            float o[4];
#pragma unroll
            for (int r = 0; r < 4; ++r) {
              o[r] = mish(fmaf(fmaf(acc[f][r], rstd, ms), go[r], bo[r])) * m;
              x2r[f * 4 + r] = o[r];
            }
            *(uint2*)&mybuf[p * 72 + 4 * q + 16 * f] =
                make_uint2(bfpair(o[0], o[1]), bfpair(o[2], o[3]));
          } else if (l == 1) {     // layer 3
            float o[4];
#pragma unroll
            for (int r = 0; r < 4; ++r)
              o[r] = mish(fmaf(fmaf(acc[f][r], rstd, ms), go[r], bo[r]));
            *(uint2*)&mybuf[p * 72 + 4 * q + 16 * f] =
                make_uint2(bfpair(o[0], o[1]), bfpair(o[2], o[3]));
          } else {                 // layer 4: *mask + residual -> cur[]
#pragma unroll
            for (int r = 0; r < 4; ++r) {
              float t1 = fmaf(fmaf(acc[f][r], rstd, ms), go[r], bo[r]);
              cur[f * 4 + r] = fmaf(mish(t1), m, x2r[f * 4 + r]);
            }
          }
        }
      }

      // ---- reduce-scatter max over the 16 points; lane p keeps value j=p ----
#pragma unroll
      for (int t = 0; t < 8; ++t) {
        float send = (lane & 8) ? cur[t] : cur[t + 8];
        float got  = __shfl_xor(send, 8);
        float mine = (lane & 8) ? cur[t + 8] : cur[t];
        cur[t] = fmaxf(mine, got);
      }
#pragma unroll
      for (int t = 0; t < 4; ++t) {
        float send = (lane & 4) ? cur[t] : cur[t + 4];
        float got  = __shfl_xor(send, 4);
        float mine = (lane & 4) ? cur[t + 4] : cur[t];
        cur[t] = fmaxf(mine, got);
      }
#pragma unroll
      for (int t = 0; t < 2; ++t) {
        float send = (lane & 2) ? cur[t] : cur[t + 2];
        float got  = __shfl_xor(send, 2);
        float mine = (lane & 2) ? cur[t + 2] : cur[t];
        cur[t] = fmaxf(mine, got);
      }
      {
        float send = (lane & 1) ? cur[0] : cur[1];
        float got  = __shfl_xor(send, 1);
        float mine = (lane & 1) ? cur[1] : cur[0];
        cur[0] = fmaxf(mine, got);
      }
      float hm = __shfl(cur[0], srcLane);   // lane L <- channel L
      if (h == 0) chmax0 = hm; else vmaxv = fmaxf(chmax0, hm);
    }
    voxelwise[v * 64 + lane] = vmaxv;       // coalesced
  }
}

// ---------------------------------------------------------------------------
// Kernel 2 v3: bfe1 + bfe2a + bfe2b via MFMA, plain bf16, cheap packs.
// ---------------------------------------------------------------------------
constexpr int XS_CH   = 72;
constexpr int XS_CELL = 16 * 72 + 16;
constexpr int ACT_OFF = 8 * XS_CELL;
constexpr int ACT_WS  = 16 * 72;
constexpr int H2_OFF  = ACT_OFF + 4 * ACT_WS;
constexpr int H2_WS   = 16 * 40;
constexpr int SMEM_SHORTS = H2_OFF + 4 * H2_WS;

__global__ __launch_bounds__(256, 4) void bfe12_mfma3_kernel(
    const float* __restrict__ voxelwise, const int* __restrict__ bevsidx,
    const float* __restrict__ bevmask,
    const short* __restrict__ w1h,
    const float* __restrict__ g1, const float* __restrict__ b1,
    const short* __restrict__ w2ah,
    const float* __restrict__ g2a, const float* __restrict__ b2a,
    const short* __restrict__ w2bh,
    const float* __restrict__ g2b, const float* __restrict__ b2b,
    float* __restrict__ x17buf)
{
  extern __shared__ short sm[];

  const int tid  = threadIdx.x;
  const int lane = tid & 63;
  const int w    = tid >> 6;
  const int r15  = lane & 15;
  const int q    = lane >> 4;
  const int cellbase = blockIdx.x * 8;

  const int chq   = lane & 3;
  const int v_loc = (lane >> 2) & 3;
  const int vblk  = lane >> 4;
  const int bit0  = v_loc & 1, bit1 = v_loc >> 1;

  int idxr[2][4];
#pragma unroll
  for (int cc = 0; cc < 2; ++cc)
#pragma unroll
    for (int vb = 0; vb < 4; ++vb) {
      int v = 16 * vb + 4 * vblk + v_loc;
      idxr[cc][vb] = bevsidx[(cellbase + 2 * w + cc) * 64 + v];
    }

  {
    short* zh = &sm[H2_OFF + w * H2_WS];
    for (int i = lane; i < 320; i += 64) zh[320 + i] = 0;
  }

  const fx4 zacc = {0.f, 0.f, 0.f, 0.f};
  short* acth = &sm[ACT_OFF + w * ACT_WS];
  short* h2h  = &sm[H2_OFF + w * H2_WS];

#pragma unroll 1
  for (int j = 0; j < 4; ++j) {
    const int g = 4 * j + w;

    __syncthreads();

#pragma unroll
    for (int cc = 0; cc < 2; ++cc) {
#pragma unroll
      for (int vb = 0; vb < 4; ++vb) {
        const float* src = voxelwise + (size_t)idxr[cc][vb] * 64 + 16 * j + 4 * chq;
        float4 f4 = *(const float4*)src;
        float a0 = f4.x, a1 = f4.y, a2 = f4.z, a3 = f4.w;
        float gv0 = bit0 ? a0 : a1, gv1 = bit0 ? a2 : a3;
        float r0 = __shfl_xor(gv0, 4), r1 = __shfl_xor(gv1, 4);
        float c0 = bit0 ? r0 : a0, c1 = bit0 ? a1 : r0;
        float c2 = bit0 ? r1 : a2, c3 = bit0 ? a3 : r1;
        float h0 = bit1 ? c0 : c2, h1 = bit1 ? c1 : c3;
        float s0 = __shfl_xor(h0, 8), s1 = __shfl_xor(h1, 8);
        float d0 = bit1 ? s0 : c0, d1 = bit1 ? s1 : c1;
        float d2 = bit1 ? c2 : s0, d3 = bit1 ? c3 : s1;
        int addr = (2 * w + cc) * XS_CELL + (4 * chq + v_loc) * XS_CH + 16 * vb + 4 * vblk;
        *(uint2*)&sm[addr] = make_uint2(bfpair(d0, d1), bfpair(d2, d3));
      }
    }

    __syncthreads();

    short8_t W1f[2][4];
#pragma unroll
    for (int c = 0; c < 2; ++c)
#pragma unroll
      for (int f = 0; f < 4; ++f) {
        int off = (g * 64 + r15 + 16 * f) * 64 + 32 * c + 8 * q;
        W1f[c][f] = *(const short8_t*)&w1h[off];
      }
    short8_t W2af[2];
#pragma unroll
    for (int c = 0; c < 2; ++c) {
      int off = (g * 16 + r15) * 64 + 32 * c + 8 * q;
      W2af[c] = *(const short8_t*)&w2ah[off];
    }
    short8_t W2bf;
    {
      int off = (g * 16 + r15) * 32 + 8 * q;
      W2bf = *(const short8_t*)&w2bh[off];
    }

#pragma unroll 1
    for (int t = 0; t < 2; ++t) {
      const int cl = r15 >> 2, p = r15 & 3;
      const int cell_loc = 4 * t + cl;
      const float bm = bevmask[cellbase + cell_loc];

      int xaddr = cell_loc * XS_CELL + (4 * w + p) * XS_CH;
      short8_t x0 = *(short8_t*)&sm[xaddr + 8 * q];
      short8_t x1 = *(short8_t*)&sm[xaddr + 32 + 8 * q];

      fx4 acc[4];
#pragma unroll
      for (int f = 0; f < 4; ++f) {
        fx4 a = __builtin_amdgcn_mfma_f32_16x16x32_bf16(W1f[0][f], x0, zacc, 0, 0, 0);
        acc[f] = __builtin_amdgcn_mfma_f32_16x16x32_bf16(W1f[1][f], x1, a, 0, 0, 0);
      }

      f32x2 s1v = {0.f, 0.f}, s2v = {0.f, 0.f};
#pragma unroll
      for (int f = 0; f < 4; ++f) {
        f32x2 a01 = __builtin_shufflevector(acc[f], acc[f], 0, 1);
        f32x2 a23 = __builtin_shufflevector(acc[f], acc[f], 2, 3);
        s1v = s1v + a01 + a23;
        s2v = __builtin_elementwise_fma(a01, a01, s2v);
        s2v = __builtin_elementwise_fma(a23, a23, s2v);
      }
      float s1 = s1v[0] + s1v[1], s2 = s2v[0] + s2v[1];
      s1 += __shfl_xor(s1, 16); s1 += __shfl_xor(s1, 32);
      s2 += __shfl_xor(s2, 16); s2 += __shfl_xor(s2, 32);
      float mean = s1 * (1.f / 64.f);
      float rstd = rsqrtf(fmaf(-mean, mean, s2 * (1.f / 64.f)) + EPS);
      float ms = -mean * rstd;

#pragma unroll
      for (int f = 0; f < 4; ++f) {
        float4 gv = *(const float4*)(g1 + g * 64 + 16 * f + 4 * q);
        float4 bv = *(const float4*)(b1 + g * 64 + 16 * f + 4 * q);
        float go[4] = {gv.x, gv.y, gv.z, gv.w};
        float bo[4] = {bv.x, bv.y, bv.z, bv.w};
        float o[4];
#pragma unroll
        for (int r = 0; r < 4; ++r)
          o[r] = mish(fmaf(fmaf(acc[f][r], rstd, ms), go[r], bo[r])) * bm;
        *(uint2*)&acth[r15 * 72 + 16 * f + 4 * q] =
            make_uint2(bfpair(o[0], o[1]), bfpair(o[2], o[3]));
      }

      short8_t a0 = *(short8_t*)&acth[r15 * 72 + 8 * q];
      short8_t a1 = *(short8_t*)&acth[r15 * 72 + 32 + 8 * q];
      fx4 a2 = __builtin_amdgcn_mfma_f32_16x16x32_bf16(W2af[0], a0, zacc, 0, 0, 0);
      a2 = __builtin_amdgcn_mfma_f32_16x16x32_bf16(W2af[1], a1, a2, 0, 0, 0);

      float sa = a2[0] + a2[1] + a2[2] + a2[3];
      float sb = fmaf(a2[0], a2[0], fmaf(a2[1], a2[1], fmaf(a2[2], a2[2], a2[3] * a2[3])));
      sa += __shfl_xor(sa, 16); sb += __shfl_xor(sb, 16);
      if (q < 2) {
        float mean2 = sa * 0.125f;
        float rstd2 = rsqrtf(fmaf(-mean2, mean2, sb * 0.125f) + EPS);
        float ms2 = -mean2 * rstd2;
        float4 gv = *(const float4*)(g2a + g * 8 + 4 * q);
        float4 bv = *(const float4*)(b2a + g * 8 + 4 * q);
        float go[4] = {gv.x, gv.y, gv.z, gv.w};
        float bo[4] = {bv.x, bv.y, bv.z, bv.w};
        float o[4];
#pragma unroll
        for (int r = 0; r < 4; ++r)
          o[r] = mish(fmaf(fmaf(a2[r], rstd2, ms2), go[r], bo[r]));
        *(uint2*)&h2h[cell_loc * 40 + p * 8 + 4 * q] =
            make_uint2(bfpair(o[0], o[1]), bfpair(o[2], o[3]));
      }
    }

    {
      short8_t bh = *(short8_t*)&h2h[r15 * 40 + 8 * q];
      fx4 a3 = __builtin_amdgcn_mfma_f32_16x16x32_bf16(W2bf, bh, zacc, 0, 0, 0);

      float sa = a3[0] + a3[1] + a3[2] + a3[3];
      float sb = fmaf(a3[0], a3[0], fmaf(a3[1], a3[1], fmaf(a3[2], a3[2], a3[3] * a3[3])));
      sa += __shfl_xor(sa, 16); sb += __shfl_xor(sb, 16);
      if (q < 2 && r15 < 8) {
        float mean3 = sa * 0.125f;
        float rstd3 = rsqrtf(fmaf(-mean3, mean3, sb * 0.125f) + EPS);
        float ms3 = -mean3 * rstd3;
        float4 gv = *(const float4*)(g2b + g * 8 + 4 * q);
        float4 bv = *(const float4*)(b2b + g * 8 + 4 * q);
        float go[4] = {gv.x, gv.y, gv.z, gv.w};
        float bo[4] = {bv.x, bv.y, bv.z, bv.w};
        float4 outv;
        float* op = &outv.x;
#pragma unroll
        for (int r = 0; r < 4; ++r)
          op[r] = mish(fmaf(fmaf(a3[r], rstd3, ms3), go[r], bo[r]));
        *(float4*)&x17buf[(size_t)(cellbase + r15) * 128 + g * 8 + 4 * q] = outv;
      }
    }
  }
}

// ---------------------------------------------------------------------------
// Kernel 3: bfe3 twice + residual + scatter via MFMA, split-precision,
// cheap split packs.
// ---------------------------------------------------------------------------
__global__ __launch_bounds__(256, 2) void bfe3_mfma2_kernel(
    const float* __restrict__ x17buf, const int* __restrict__ bevcoors,
    const short* __restrict__ w3h, const short* __restrict__ w3l,
    const float* __restrict__ g3, const float* __restrict__ b3,
    float* __restrict__ out)
{
  __shared__ short x18h[4][16 * 136];
  __shared__ short x18l[4][16 * 136];

  const int tid  = threadIdx.x;
  const int lane = tid & 63;
  const int w    = tid >> 6;
  const int r15  = lane & 15;
  const int q    = lane >> 4;
  const int cell = blockIdx.x * 64 + w * 16 + r15;
  const float* xr = x17buf + (size_t)cell * 128;
  short* xh18 = &x18h[w][0];
  short* xl18 = &x18l[w][0];
  const fx4 zacc = {0.f, 0.f, 0.f, 0.f};

  short8_t xh[4], xl[4];
#pragma unroll
  for (int c = 0; c < 4; ++c) {
    const float* s = xr + 32 * c + 8 * q;
    float4 A = *(const float4*)s;
    float4 B = *(const float4*)(s + 4);
    float t[8] = {A.x, A.y, A.z, A.w, B.x, B.y, B.z, B.w};
    unsigned hu[4], lu[4];
#pragma unroll
    for (int jj = 0; jj < 4; ++jj) {
      float la, lb;
      hu[jj] = hipack(t[2 * jj], t[2 * jj + 1], la, lb);
      lu[jj] = bfpair(la, lb);
    }
    xh[c] = __builtin_bit_cast(short8_t, make_uint4(hu[0], hu[1], hu[2], hu[3]));
    xl[c] = __builtin_bit_cast(short8_t, make_uint4(lu[0], lu[1], lu[2], lu[3]));
  }

  fx4 acc[8];
#pragma unroll
  for (int f = 0; f < 8; ++f) {
    fx4 a = zacc;
#pragma unroll
    for (int c = 0; c < 4; ++c) {
      int off = (16 * f + r15) * 128 + 32 * c + 8 * q;
      short8_t Ah = *(const short8_t*)&w3h[off];
      short8_t Al = *(const short8_t*)&w3l[off];
      a = __builtin_amdgcn_mfma_f32_16x16x32_bf16(Ah, xh[c], a, 0, 0, 0);
      a = __builtin_amdgcn_mfma_f32_16x16x32_bf16(Ah, xl[c], a, 0, 0, 0);
      a = __builtin_amdgcn_mfma_f32_16x16x32_bf16(Al, xh[c], a, 0, 0, 0);
    }
    acc[f] = a;
  }
  {
    f32x2 s1v = {0.f, 0.f}, s2v = {0.f, 0.f};
#pragma unroll
    for (int f = 0; f < 8; ++f) {
      f32x2 a01 = __builtin_shufflevector(acc[f], acc[f], 0, 1);
      f32x2 a23 = __builtin_shufflevector(acc[f], acc[f], 2, 3);
      s1v = s1v + a01 + a23;
      s2v = __builtin_elementwise_fma(a01, a01, s2v);
      s2v = __builtin_elementwise_fma(a23, a23, s2v);
    }
    float s1 = s1v[0] + s1v[1], s2 = s2v[0] + s2v[1];
    s1 += __shfl_xor(s1, 16); s1 += __shfl_xor(s1, 32);
    s2 += __shfl_xor(s2, 16); s2 += __shfl_xor(s2, 32);
    float mean = s1 * (1.f / 128.f);
    float rstd = rsqrtf(fmaf(-mean, mean, s2 * (1.f / 128.f)) + EPS);
    float ms = -mean * rstd;
#pragma unroll
    for (int f = 0; f < 8; ++f) {
      float4 gv = *(const float4*)(g3 + 16 * f + 4 * q);
      float4 bv = *(const float4*)(b3 + 16 * f + 4 * q);
      float go[4] = {gv.x, gv.y, gv.z, gv.w};
      float bo[4] = {bv.x, bv.y, bv.z, bv.w};
      float o[4];
#pragma unroll
      for (int r = 0; r < 4; ++r)
        o[r] = mish(fmaf(fmaf(acc[f][r], rstd, ms), go[r], bo[r]));
      float la0, lb0, la1, lb1;
      unsigned h01 = hipack(o[0], o[1], la0, lb0);
      unsigned h23 = hipack(o[2], o[3], la1, lb1);
      *(uint2*)&xh18[r15 * 136 + 16 * f + 4 * q] = make_uint2(h01, h23);
      *(uint2*)&xl18[r15 * 136 + 16 * f + 4 * q] =
          make_uint2(bfpair(la0, lb0), bfpair(la1, lb1));
    }
  }

  short8_t yh[4], yl[4];
#pragma unroll
  for (int c = 0; c < 4; ++c) {
    yh[c] = *(short8_t*)&xh18[r15 * 136 + 32 * c + 8 * q];
    yl[c] = *(short8_t*)&xl18[r15 * 136 + 32 * c + 8 * q];
  }
#pragma unroll
  for (int f = 0; f < 8; ++f) {
    fx4 a = zacc;
#pragma unroll
    for (int c = 0; c < 4; ++c) {
      int off = (16 * f + r15) * 128 + 32 * c + 8 * q;
      short8_t Ah = *(const short8_t*)&w3h[off];
      short8_t Al = *(const short8_t*)&w3l[off];
      a = __builtin_amdgcn_mfma_f32_16x16x32_bf16(Ah, yh[c], a, 0, 0, 0);
      a = __builtin_amdgcn_mfma_f32_16x16x32_bf16(Ah, yl[c], a, 0, 0, 0);
      a = __builtin_amdgcn_mfma_f32_16x16x32_bf16(Al, yh[c], a, 0, 0, 0);
    }
    acc[f] = a;
  }
  {
    f32x2 s1v = {0.f, 0.f}, s2v = {0.f, 0.f};
#pragma unroll
    for (int f = 0; f < 8; ++f) {
      f32x2 a01 = __builtin_shufflevector(acc[f], acc[f], 0, 1);
      f32x2 a23 = __builtin_shufflevector(acc[f], acc[f], 2, 3);
      s1v = s1v + a01 + a23;
      s2v = __builtin_elementwise_fma(a01, a01, s2v);
      s2v = __builtin_elementwise_fma(a23, a23, s2v);
    }
    float s1 = s1v[0] + s1v[1], s2 = s2v[0] + s2v[1];
    s1 += __shfl_xor(s1, 16); s1 += __shfl_xor(s1, 32);
    s2 += __shfl_xor(s2, 16); s2 += __shfl_xor(s2, 32);
    float mean = s1 * (1.f / 128.f);
    float rstd = rsqrtf(fmaf(-mean, mean, s2 * (1.f / 128.f)) + EPS);
    float ms = -mean * rstd;

    int2 hw2 = *(const int2*)&bevcoors[cell * 2];   // (h, w)
    const int base = hw2.y * BEV_H + hw2.x;
#pragma unroll
    for (int f = 0; f < 8; ++f) {
      float4 gv = *(const float4*)(g3 + 16 * f + 4 * q);
      float4 bv = *(const float4*)(b3 + 16 * f + 4 * q);
      float go[4] = {gv.x, gv.y, gv.z, gv.w};
      float bo[4] = {bv.x, bv.y, bv.z, bv.w};
      float4 R = *(const float4*)(xr + 16 * f + 4 * q);
      float Ra[4] = {R.x, R.y, R.z, R.w};
#pragma unroll
      for (int r = 0; r < 4; ++r) {
        float t1 = fmaf(fmaf(acc[f][r], rstd, ms), go[r], bo[r]);
        float val = mish(t1) + Ra[r];
        out[(size_t)(16 * f + 4 * q + r) * HW + base] = val;
      }
    }
  }
}

// ---------------------------------------------------------------------------
extern "C" void kernel_launch(void* const* d_in, const int* in_sizes, int n_in,
                              void* d_out, int out_size, void* d_ws, size_t ws_size,
                              hipStream_t stream) {
  const float* voxels   = (const float*)d_in[0];
  const float* vmask    = (const float*)d_in[1];
  const int*   bevsidx  = (const int*)d_in[2];
  const int*   bevcoors = (const int*)d_in[3];
  const float* bevmask  = (const float*)d_in[4];
  const float* vfe1_W = (const float*)d_in[5];
  const float* vfe1_g = (const float*)d_in[6];
  const float* vfe1_b = (const float*)d_in[7];
  const float* vfe2_W = (const float*)d_in[8];
  const float* vfe2_g = (const float*)d_in[9];
  const float* vfe2_b = (const float*)d_in[10];
  const float* vfe3_W = (const float*)d_in[11];
  const float* vfe3_g = (const float*)d_in[12];
  const float* vfe3_b = (const float*)d_in[13];
  const float* vfe4_W = (const float*)d_in[14];
  const float* vfe4_g = (const float*)d_in[15];
  const float* vfe4_b = (const float*)d_in[16];
  const float* bfe1_W  = (const float*)d_in[17];
  const float* bfe1_g  = (const float*)d_in[18];
  const float* bfe1_b  = (const float*)d_in[19];
  const float* bfe2a_W = (const float*)d_in[20];
  const float* bfe2a_g = (const float*)d_in[21];
  const float* bfe2a_b = (const float*)d_in[22];
  const float* bfe2b_W = (const float*)d_in[23];
  const float* bfe2b_g = (const float*)d_in[24];
  const float* bfe2b_b = (const float*)d_in[25];
  const float* bfe3_W  = (const float*)d_in[26];
  const float* bfe3_g  = (const float*)d_in[27];
  const float* bfe3_b  = (const float*)d_in[28];

  float* voxelwise = (float*)d_ws;                    // NV*CV floats
  float* x17buf    = voxelwise + NV * CV;             // NB*128 floats
  short* wbase     = (short*)(x17buf + (size_t)NB * 128);
  short* w1h  = wbase;                                // 65536
  short* w1l  = w1h + 65536;
  short* w2ah = w1l + 65536;                          // 16384
  short* w2al = w2ah + 16384;
  short* w2bh = w2al + 16384;                         // 8192
  short* w2bl = w2bh + 8192;
  short* w3h  = w2bl + 8192;                          // 16384
  short* w3l  = w3h + 16384;
  float* out = (float*)d_out;

  hipMemsetAsync(d_out, 0, (size_t)out_size * sizeof(float), stream);

  pack_weights_kernel<<<(106496 + 255) / 256, 256, 0, stream>>>(
      bfe1_W, bfe2a_W, bfe2b_W, bfe3_W,
      w1h, w1l, w2ah, w2al, w2bh, w2bl, w3h, w3l);

  vfe_mfma4_kernel<<<NV / 16, 256, 0, stream>>>(
      voxels, vmask,
      vfe1_W, vfe1_g, vfe1_b, vfe2_W, vfe2_g, vfe2_b,
      vfe3_W, vfe3_g, vfe3_b, vfe4_W, vfe4_g, vfe4_b,
      voxelwise);

  bfe12_mfma3_kernel<<<NB / 8, 256, SMEM_SHORTS * sizeof(short), stream>>>(
      voxelwise, bevsidx, bevmask,
      w1h, bfe1_g, bfe1_b,
      w2ah, bfe2a_g, bfe2a_b,
      w2bh, bfe2b_g, bfe2b_b,
      x17buf);

  bfe3_mfma2_kernel<<<NB / 64, 256, 0, stream>>>(
      x17buf, bevcoors, w3h, w3l, bfe3_g, bfe3_b, out);
}